// Round 6
// baseline (232.849 us; speedup 1.0000x reference)
//
#include <hip/hip_runtime.h>

typedef unsigned short ushort_t;
typedef unsigned int uint32;
typedef __attribute__((ext_vector_type(8))) short short8;
typedef __attribute__((ext_vector_type(4))) float f32x4;

#define VMCNT(N) asm volatile("s_waitcnt vmcnt(" #N ")" ::: "memory")

static __device__ __forceinline__ ushort_t f2bf(float f) {
  uint32 u = __builtin_bit_cast(uint32, f);
  u += 0x7fffu + ((u >> 16) & 1u);   // round-to-nearest-even
  return (ushort_t)(u >> 16);
}

static __device__ __forceinline__ void gload_lds16(const ushort_t* g, ushort_t* l) {
  __builtin_amdgcn_global_load_lds(
      (const __attribute__((address_space(1))) uint32*)g,
      (__attribute__((address_space(3))) uint32*)l, 16, 0, 0);
}

static __device__ __forceinline__ void addcvt4(const float* __restrict__ a,
                                               const float* __restrict__ b,
                                               ushort_t* __restrict__ o, int i) {
  float4 va = reinterpret_cast<const float4*>(a)[i];
  if (b != nullptr) {
    float4 vb = reinterpret_cast<const float4*>(b)[i];
    va.x += vb.x; va.y += vb.y; va.z += vb.z; va.w += vb.w;
  }
  ushort4 u;
  u.x = f2bf(va.x); u.y = f2bf(va.y); u.z = f2bf(va.z); u.w = f2bf(va.w);
  reinterpret_cast<ushort4*>(o)[i] = u;
}

// ---------------------------------------------------------------------------
// prep1: f2p = bf16(f2+f2pe), weights fp32->bf16, bqc concat, Z zero.
// ---------------------------------------------------------------------------
__global__ void prep1_kernel(const float* __restrict__ f2, const float* __restrict__ f2pe,
                             const float* __restrict__ Wq1, const float* __restrict__ Wq2,
                             const float* __restrict__ Wk1, const float* __restrict__ Wv1,
                             const float* __restrict__ Wk2, const float* __restrict__ Wv2,
                             const float* __restrict__ bq1, const float* __restrict__ bq2,
                             ushort_t* __restrict__ f2p, ushort_t* __restrict__ WqB,
                             ushort_t* __restrict__ Wk1B, ushort_t* __restrict__ Wv1B,
                             ushort_t* __restrict__ Wk2B, ushort_t* __restrict__ Wv2B,
                             float* __restrict__ bqc, float* __restrict__ Z) {
  int b = blockIdx.x, t = threadIdx.x;
  if (b < 16384) {
    addcvt4(f2, f2pe, f2p, b * 256 + t);
  } else if (b < 17920) {
    int u = b - 16384;
    int arr = u >> 8, i = (u & 255) * 256 + t;
    const float* s; ushort_t* d;
    switch (arr) {
      case 0: s = Wq1; d = WqB; break;
      case 1: s = Wq2; d = WqB + 262144; break;
      case 2: s = Wk1; d = Wk1B; break;
      case 3: s = Wv1; d = Wv1B; break;
      case 4: s = Wk2; d = Wk2B; break;
      default: s = Wv2; d = Wv2B; break;
    }
    addcvt4(s, nullptr, d, i);
  } else {
    for (int i = t; i < 512; i += 256) { bqc[i] = bq1[i]; bqc[512 + i] = bq2[i]; }
    for (int i = t; i < 8192; i += 256) Z[i] = 0.f;
  }
}

// ---------------------------------------------------------------------------
// prep2: kv inputs, single pass per source (writes both +pe and plain), + ctx 0.
// grid = 5632.
// ---------------------------------------------------------------------------
__global__ void prep2_kernel(const float* __restrict__ f3, const float* __restrict__ f3pe,
                             const float* __restrict__ f4, const float* __restrict__ f4pe,
                             ushort_t* __restrict__ f3p, ushort_t* __restrict__ f3b,
                             ushort_t* __restrict__ f4p, ushort_t* __restrict__ f4b,
                             float* __restrict__ ctx) {
  int b = blockIdx.x, t = threadIdx.x;
  if (b < 4096) {
    int i = b * 256 + t;
    float4 va = reinterpret_cast<const float4*>(f3)[i];
    float4 vp = reinterpret_cast<const float4*>(f3pe)[i];
    ushort4 ub, up;
    ub.x = f2bf(va.x); ub.y = f2bf(va.y); ub.z = f2bf(va.z); ub.w = f2bf(va.w);
    up.x = f2bf(va.x + vp.x); up.y = f2bf(va.y + vp.y);
    up.z = f2bf(va.z + vp.z); up.w = f2bf(va.w + vp.w);
    reinterpret_cast<ushort4*>(f3b)[i] = ub;
    reinterpret_cast<ushort4*>(f3p)[i] = up;
  } else if (b < 5120) {
    int i = (b - 4096) * 256 + t;
    float4 va = reinterpret_cast<const float4*>(f4)[i];
    float4 vp = reinterpret_cast<const float4*>(f4pe)[i];
    ushort4 ub, up;
    ub.x = f2bf(va.x); ub.y = f2bf(va.y); ub.z = f2bf(va.z); ub.w = f2bf(va.w);
    up.x = f2bf(va.x + vp.x); up.y = f2bf(va.y + vp.y);
    up.z = f2bf(va.z + vp.z); up.w = f2bf(va.w + vp.w);
    reinterpret_cast<ushort4*>(f4b)[i] = ub;
    reinterpret_cast<ushort4*>(f4p)[i] = up;
  } else {
    reinterpret_cast<float4*>(ctx)[(b - 5120) * 256 + t] = make_float4(0.f, 0.f, 0.f, 0.f);
  }
}

// ---------------------------------------------------------------------------
// 256x256 8-wave counted-vmcnt GEMM (T2+T3+T4+T5).  C[M,N] = A[M,K] @ Bt[N,K]^T.
// BK=64, dbuf LDS 128KB, 4 quadrant phases/K-tile of 16 MFMA each.
// Stage order per tile (issued during previous tile): {A0,A2,B0,B1,B2,B3,A1,A3};
// boundary wait vmcnt(2) covers all but {A1,A3}; mid-tile vmcnt(4) covers those.
// MODE 0: E=exp(+bias), Z colsums (N=1024).  MODE 2: fp32 out (N=512, batched Bt).
// ---------------------------------------------------------------------------
template<int NT, int MODE>
__global__ __launch_bounds__(512, 1)
void gemm256(const ushort_t* __restrict__ A, const ushort_t* __restrict__ Bt,
             const float* __restrict__ bias, void* __restrict__ Cout,
             float* __restrict__ Z) {
  constexpr int K = NT * 64;
  constexpr int NTILES = (MODE == 0) ? 4 : 2;
  extern __shared__ ushort_t smem[];
  ushort_t* sA = smem;            // 2 x 256 x 64
  ushort_t* sB = smem + 32768;    // 2 x 256 x 64

  const int cpx = gridDim.x >> 3;
  const int swz = (blockIdx.x & 7) * cpx + (blockIdx.x >> 3);
  const int mBase = (swz / NTILES) * 256, nBase = (swz % NTILES) * 256;

  const ushort_t* Bp = Bt;
  if (MODE == 2) Bp += (size_t)(mBase >> 12) * 524288;   // per-batch Mt

  const int t = threadIdx.x;
  const int w = t >> 6, l = t & 63;
  const int l15 = l & 15, l4 = l >> 4;
  const int lrow = l >> 3;
  const int srcO = ((l & 7) ^ lrow) << 3;     // inverse-swizzled src col (elems)
  const int wm = w >> 2, wn = w & 3;          // wave grid 2M x 4N

  f32x4 acc[8][4];
#pragma unroll
  for (int i = 0; i < 8; i++)
#pragma unroll
    for (int j = 0; j < 4; j++) acc[i][j] = (f32x4){0.f, 0.f, 0.f, 0.f};
  short8 bf[4][2];

  auto stA = [&](int e, int r, int k0) {
    gload_lds16(A + (size_t)(mBase + r * 64 + w * 8 + lrow) * K + k0 + srcO,
                sA + e * 16384 + r * 4096 + w * 512);
  };
  auto stB = [&](int e, int r, int k0) {
    gload_lds16(Bp + (size_t)(nBase + r * 64 + w * 8 + lrow) * K + k0 + srcO,
                sB + e * 16384 + r * 4096 + w * 512);
  };

  // prologue: stage tile 0 into buf 0, full drain once
  stA(0, 0, 0); stA(0, 2, 0); stB(0, 0, 0); stB(0, 1, 0);
  stB(0, 2, 0); stB(0, 3, 0); stA(0, 1, 0); stA(0, 3, 0);
  VMCNT(0);
  __builtin_amdgcn_s_barrier();

#define PHASE(q, FIRST)                                                        \
  {                                                                            \
    if (!last) {                                                               \
      if (q == 0) { stA(e, 0, k1); stA(e, 2, k1); }                            \
      if (q == 1) { stB(e, 0, k1); stB(e, 1, k1); }                            \
      if (q == 2) { stB(e, 2, k1); stB(e, 3, k1); }                            \
      if (q == 3) { stA(e, 1, k1); stA(e, 3, k1); }                            \
    }                                                                          \
    short8 af[2][2];                                                           \
    const char* AsB = (const char*)(sA + d * 16384);                           \
    _Pragma("unroll") for (int i = 0; i < 2; i++)                              \
      _Pragma("unroll") for (int kk = 0; kk < 2; kk++) {                       \
        int rowA = wm * 128 + (q * 2 + i) * 16 + l15;                          \
        af[i][kk] = *(const short8*)(AsB + rowA * 128 +                        \
                      ((kk * 64 + l4 * 16) ^ ((rowA & 7) << 4)));              \
      }                                                                        \
    if (FIRST) {                                                               \
      const char* BsB = (const char*)(sB + d * 16384);                         \
      _Pragma("unroll") for (int fn = 0; fn < 4; fn++)                         \
        _Pragma("unroll") for (int kk = 0; kk < 2; kk++) {                     \
          int rowB = wn * 64 + fn * 16 + l15;                                  \
          bf[fn][kk] = *(const short8*)(BsB + rowB * 128 +                     \
                         ((kk * 64 + l4 * 16) ^ ((rowB & 7) << 4)));           \
        }                                                                      \
    }                                                                          \
    __builtin_amdgcn_sched_barrier(0);                                         \
    __builtin_amdgcn_s_barrier();                                              \
    __builtin_amdgcn_sched_barrier(0);                                         \
    __builtin_amdgcn_s_setprio(1);                                             \
    _Pragma("unroll") for (int i = 0; i < 2; i++)                              \
      _Pragma("unroll") for (int fn = 0; fn < 4; fn++)                         \
        _Pragma("unroll") for (int kk = 0; kk < 2; kk++)                       \
          acc[q * 2 + i][fn] = __builtin_amdgcn_mfma_f32_16x16x32_bf16(        \
              af[i][kk], bf[fn][kk], acc[q * 2 + i][fn], 0, 0, 0);             \
    __builtin_amdgcn_s_setprio(0);                                             \
    __builtin_amdgcn_sched_barrier(0);                                         \
    if (q == 1) { if (last) { VMCNT(0); } else { VMCNT(4); } }                 \
    if (q == 3) { if (!last) { VMCNT(2); } }                                   \
    __builtin_amdgcn_s_barrier();                                              \
    __builtin_amdgcn_sched_barrier(0);                                         \
  }

#pragma unroll 2
  for (int ti = 0; ti < NT; ++ti) {
    const bool last = (ti == NT - 1);
    const int d = ti & 1, e = d ^ 1;
    const int k1 = ti * 64 + 64;
    PHASE(0, true)
    PHASE(1, false)
    PHASE(2, false)
    PHASE(3, false)
  }
#undef PHASE

  // ---- epilogue; C/D layout: col = lane&15, row = (lane>>4)*4 + reg ----
  if (MODE == 0) {
    ushort_t* E = (ushort_t*)Cout;
    const int N = 1024;
    const int batch = mBase >> 12;
#pragma unroll
    for (int fn = 0; fn < 4; fn++) {
      int col = nBase + wn * 64 + fn * 16 + l15;
      float bcol = bias[col];
      float csum = 0.f;
#pragma unroll
      for (int fm = 0; fm < 8; fm++) {
#pragma unroll
        for (int r = 0; r < 4; r++) {
          int row = mBase + wm * 128 + fm * 16 + l4 * 4 + r;
          float e = __expf(acc[fm][fn][r] + bcol);
          E[(size_t)row * N + col] = f2bf(e);
          csum += e;
        }
      }
      csum += __shfl_xor(csum, 16);
      csum += __shfl_xor(csum, 32);
      if (l4 == 0) atomicAdd(&Z[batch * 1024 + col], csum);
    }
  } else {
    float* C = (float*)Cout;
    const int N = 512;
#pragma unroll
    for (int fn = 0; fn < 4; fn++) {
      int col = nBase + wn * 64 + fn * 16 + l15;
      float bcol = bias[col];
#pragma unroll
      for (int fm = 0; fm < 8; fm++)
#pragma unroll
        for (int r = 0; r < 4; r++) {
          int row = mBase + wm * 128 + fm * 16 + l4 * 4 + r;
          C[(size_t)row * N + col] = acc[fm][fn][r] + bcol;
        }
    }
  }
}

// ---------------------------------------------------------------------------
// 128x128 GEMM core (4 waves) for the kv quad: global_load_lds staging.
// ---------------------------------------------------------------------------
static __device__ __forceinline__ void gemm_core(
    const ushort_t* __restrict__ A, const ushort_t* __restrict__ Bt,
    int K, int mBase, int nBase, ushort_t* As, ushort_t* Bs, f32x4 acc[4][4]) {
  const int t = threadIdx.x;
  const int w = t >> 6, l = t & 63;
  const int l15 = l & 15, l4 = l >> 4;
  const int rowInSeg = l >> 3;
  const int srcOff = ((l & 7) ^ rowInSeg) << 3;
  const int wm = (w >> 1) * 64, wn = (w & 1) * 64;

  for (int k0 = 0; k0 < K; k0 += 64) {
#pragma unroll
    for (int i = 0; i < 4; i++) {
      int seg = w * 4 + i;
      int row = seg * 8 + rowInSeg;
      gload_lds16(A + (size_t)(mBase + row) * K + k0 + srcOff, As + seg * 512);
      gload_lds16(Bt + (size_t)(nBase + row) * K + k0 + srcOff, Bs + seg * 512);
    }
    __syncthreads();
#pragma unroll
    for (int kk = 0; kk < 2; kk++) {
      short8 af[4], bfr[4];
      const int kb = kk * 64 + l4 * 16;
#pragma unroll
      for (int f = 0; f < 4; f++) {
        int rowA = wm + f * 16 + l15;
        af[f] = *reinterpret_cast<const short8*>(
            reinterpret_cast<const char*>(As) + rowA * 128 + (kb ^ ((rowA & 7) << 4)));
        int rowB = wn + f * 16 + l15;
        bfr[f] = *reinterpret_cast<const short8*>(
            reinterpret_cast<const char*>(Bs) + rowB * 128 + (kb ^ ((rowB & 7) << 4)));
      }
#pragma unroll
      for (int fm = 0; fm < 4; fm++)
#pragma unroll
        for (int fn = 0; fn < 4; fn++)
          acc[fm][fn] = __builtin_amdgcn_mfma_f32_16x16x32_bf16(af[fm], bfr[fn], acc[fm][fn], 0, 0, 0);
    }
    __syncthreads();
  }
}

// ---------------------------------------------------------------------------
// KV quad: all four kv GEMMs (N=512, K=512) in one 640-block launch,
// k-softmax fused in epilogue. XCD-chunked swizzle.
// ---------------------------------------------------------------------------
__global__ __launch_bounds__(256, 4)
void kv_quad(const ushort_t* __restrict__ f3p, const ushort_t* __restrict__ f3b,
             const ushort_t* __restrict__ f4p, const ushort_t* __restrict__ f4b,
             const ushort_t* __restrict__ Wk1B, const ushort_t* __restrict__ Wv1B,
             const ushort_t* __restrict__ Wk2B, const ushort_t* __restrict__ Wv2B,
             const float* __restrict__ bk1, const float* __restrict__ bv1,
             const float* __restrict__ bk2, const float* __restrict__ bv2,
             ushort_t* __restrict__ ks3, ushort_t* __restrict__ v3,
             ushort_t* __restrict__ ks4, ushort_t* __restrict__ v4) {
  __shared__ ushort_t As[8192], Bs[8192];
  const int bid = blockIdx.x;
  const int id = (bid & 7) * 80 + (bid >> 3);
  const ushort_t* A; const ushort_t* Bt; const float* bias; ushort_t* out;
  bool doSM; int loc;
  if (id < 256)      { A = f3p; Bt = Wk1B; bias = bk1; out = ks3; doSM = true;  loc = id; }
  else if (id < 512) { A = f3b; Bt = Wv1B; bias = bv1; out = v3;  doSM = false; loc = id - 256; }
  else if (id < 576) { A = f4p; Bt = Wk2B; bias = bk2; out = ks4; doSM = true;  loc = id - 512; }
  else               { A = f4b; Bt = Wv2B; bias = bv2; out = v4;  doSM = false; loc = id - 576; }
  const int nBase = (loc & 3) * 128, mBase = (loc >> 2) * 128;
  const int t = threadIdx.x, w = t >> 6, lane = t & 63;
  const int l15 = lane & 15, l4 = lane >> 4;
  const int wm = (w >> 1) * 64, wn = (w & 1) * 64;

  f32x4 acc[4][4];
#pragma unroll
  for (int i = 0; i < 4; i++)
#pragma unroll
    for (int j = 0; j < 4; j++) acc[i][j] = (f32x4){0.f, 0.f, 0.f, 0.f};

  gemm_core(A, Bt, 512, mBase, nBase, As, Bs, acc);

  const int N = 512;
  float bcol[4];
#pragma unroll
  for (int fn = 0; fn < 4; fn++) bcol[fn] = bias[nBase + wn + fn * 16 + l15];

  if (doSM) {
#pragma unroll
    for (int fm = 0; fm < 4; fm++) {
#pragma unroll
      for (int r = 0; r < 4; r++) {
        float x[4], m = -1e30f;
#pragma unroll
        for (int fn = 0; fn < 4; fn++) { x[fn] = acc[fm][fn][r] + bcol[fn]; m = fmaxf(m, x[fn]); }
        m = fmaxf(m, __shfl_xor(m, 1));
        m = fmaxf(m, __shfl_xor(m, 2));
        m = fmaxf(m, __shfl_xor(m, 4));
        m = fmaxf(m, __shfl_xor(m, 8));
        float s = 0.f;
#pragma unroll
        for (int fn = 0; fn < 4; fn++) { x[fn] = __expf(x[fn] - m); s += x[fn]; }
        s += __shfl_xor(s, 1);
        s += __shfl_xor(s, 2);
        s += __shfl_xor(s, 4);
        s += __shfl_xor(s, 8);
        float inv = 1.f / s;
        int row = mBase + wm + fm * 16 + l4 * 4 + r;
#pragma unroll
        for (int fn = 0; fn < 4; fn++)
          out[(size_t)row * N + nBase + wn + fn * 16 + l15] = f2bf(x[fn] * inv);
      }
    }
  } else {
#pragma unroll
    for (int fn = 0; fn < 4; fn++) {
      int col = nBase + wn + fn * 16 + l15;
#pragma unroll
      for (int fm = 0; fm < 4; fm++)
#pragma unroll
        for (int r = 0; r < 4; r++) {
          int row = mBase + wm + fm * 16 + l4 * 4 + r;
          out[(size_t)row * N + col] = f2bf(acc[fm][fn][r] + bcol[fn]);
        }
    }
  }
}

// ---------------------------------------------------------------------------
// ctx[bh,d,e] += sum_{n in chunk} ks[b,n,h*64+d] * v[b,n,h*64+e]
// ---------------------------------------------------------------------------
__global__ __launch_bounds__(256)
void ctx_kernel(const ushort_t* __restrict__ ks, const ushort_t* __restrict__ v,
                float* __restrict__ ctxOut, int Nk, int nChunks) {
  __shared__ float ks_s[64][68];
  __shared__ float v_s[64][68];
  int bh = blockIdx.x / nChunks;
  int chunk = blockIdx.x - bh * nChunks;
  int b = bh >> 3, h = bh & 7;
  int t = threadIdx.x;
  int td = t & 15, te = t >> 4;
  float acc[4][4] = {};
  size_t rowBase = (size_t)b * Nk + chunk * 256;
  for (int n0 = 0; n0 < 256; n0 += 64) {
#pragma unroll
    for (int i = 0; i < 16; i++) {
      int idx = i * 256 + t;
      int n = idx >> 6, d = idx & 63;
      size_t g = (rowBase + n0 + n) * 512 + h * 64 + d;
      ks_s[n][d] = __builtin_bit_cast(float, (uint32)ks[g] << 16);
      v_s[n][d] = __builtin_bit_cast(float, (uint32)v[g] << 16);
    }
    __syncthreads();
#pragma unroll 8
    for (int n = 0; n < 64; n++) {
      float4 cv = *reinterpret_cast<const float4*>(&ks_s[n][td * 4]);
      float4 vv = *reinterpret_cast<const float4*>(&v_s[n][te * 4]);
      float ca[4] = {cv.x, cv.y, cv.z, cv.w};
      float va[4] = {vv.x, vv.y, vv.z, vv.w};
#pragma unroll
      for (int i = 0; i < 4; i++)
#pragma unroll
        for (int j = 0; j < 4; j++) acc[i][j] += ca[i] * va[j];
    }
    __syncthreads();
  }
  float* dst = ctxOut + (size_t)bh * 4096;
#pragma unroll
  for (int i = 0; i < 4; i++)
#pragma unroll
    for (int j = 0; j < 4; j++)
      atomicAdd(&dst[(td * 4 + i) * 64 + te * 4 + j], acc[i][j]);
}

// ---------------------------------------------------------------------------
// Fold: Mt[b][j][c] = (sum_e ctx[branch,b,h,d,e]*Wr[j, branch*512+h*64+e]) / Z[b,c]
// ---------------------------------------------------------------------------
__global__ __launch_bounds__(256)
void fold_kernel(const float* __restrict__ ctx, const float* __restrict__ Wr,
                 const float* __restrict__ Z, ushort_t* __restrict__ Mt) {
  __shared__ float ctxT[64][68];   // [e][d]
  __shared__ float wrT[64][68];    // [e][jl]
  __shared__ float zinv[64];
  int blk = blockIdx.x;
  int jc = blk & 7;
  int h = (blk >> 3) & 7;
  int branch = (blk >> 6) & 1;
  int b = blk >> 7;
  int t = threadIdx.x;
  int cbase = branch * 512 + h * 64;
  const float* csrc = ctx + (size_t)(branch * 64 + b * 8 + h) * 4096;
#pragma unroll
  for (int i = 0; i < 16; i++) {
    int idx = i * 256 + t;
    int d = idx >> 6, e = idx & 63;
    ctxT[e][d] = csrc[d * 64 + e];
  }
#pragma unroll
  for (int i = 0; i < 16; i++) {
    int idx = i * 256 + t;
    int jl = idx >> 6, e = idx & 63;
    wrT[e][jl] = Wr[(size_t)(jc * 64 + jl) * 1024 + cbase + e];
  }
  if (t < 64) zinv[t] = 1.0f / Z[b * 1024 + cbase + t];
  __syncthreads();
  int td = t & 15, tj = t >> 4;
  float acc[4][4] = {};   // [d_i][jj]
#pragma unroll 8
  for (int e = 0; e < 64; e++) {
    float4 cv = *reinterpret_cast<const float4*>(&ctxT[e][td * 4]);
    float4 wv = *reinterpret_cast<const float4*>(&wrT[e][tj * 4]);
    float ca[4] = {cv.x, cv.y, cv.z, cv.w};
    float wa[4] = {wv.x, wv.y, wv.z, wv.w};
#pragma unroll
    for (int i = 0; i < 4; i++)
#pragma unroll
      for (int jj = 0; jj < 4; jj++) acc[i][jj] += ca[i] * wa[jj];
  }
  float zi[4] = {zinv[td * 4], zinv[td * 4 + 1], zinv[td * 4 + 2], zinv[td * 4 + 3]};
#pragma unroll
  for (int jj = 0; jj < 4; jj++) {
    ushort4 u;
    u.x = f2bf(acc[0][jj] * zi[0]);
    u.y = f2bf(acc[1][jj] * zi[1]);
    u.z = f2bf(acc[2][jj] * zi[2]);
    u.w = f2bf(acc[3][jj] * zi[3]);
    *reinterpret_cast<ushort4*>(
        &Mt[(size_t)(b * 512 + jc * 64 + tj * 4 + jj) * 1024 + cbase + td * 4]) = u;
  }
}

// ---------------------------------------------------------------------------
extern "C" void kernel_launch(void* const* d_in, const int* in_sizes, int n_in,
                              void* d_out, int out_size, void* d_ws, size_t ws_size,
                              hipStream_t stream) {
  const float* f2 = (const float*)d_in[0];
  const float* f3 = (const float*)d_in[1];
  const float* f4 = (const float*)d_in[2];
  const float* f2pe = (const float*)d_in[3];
  const float* f3pe = (const float*)d_in[4];
  const float* f4pe = (const float*)d_in[5];
  const float* Wq1 = (const float*)d_in[6];
  const float* bq1 = (const float*)d_in[7];
  const float* Wk1 = (const float*)d_in[8];
  const float* bk1 = (const float*)d_in[9];
  const float* Wv1 = (const float*)d_in[10];
  const float* bv1 = (const float*)d_in[11];
  const float* Wq2 = (const float*)d_in[12];
  const float* bq2 = (const float*)d_in[13];
  const float* Wk2 = (const float*)d_in[14];
  const float* bk2 = (const float*)d_in[15];
  const float* Wv2 = (const float*)d_in[16];
  const float* bv2 = (const float*)d_in[17];
  const float* Wr = (const float*)d_in[18];
  const float* br = (const float*)d_in[19];

  char* ws = (char*)d_ws;
  // Region 0: E bf16 [32768,1024]
  ushort_t* E = (ushort_t*)(ws + 0);                       // 67,108,864 B
  // Region 1: f2p (live prep1->g1), then reused by prep2 outputs (after g1)
  char* R1 = ws + 67108864;
  ushort_t* f2p = (ushort_t*)R1;
  ushort_t* f3p = (ushort_t*)R1;                           // 8,388,608
  ushort_t* f3b = (ushort_t*)(R1 + 8388608);               // 8,388,608
  ushort_t* f4p = (ushort_t*)(R1 + 16777216);              // 2,097,152
  ushort_t* f4b = (ushort_t*)(R1 + 18874368);              // 2,097,152
  float* ctx = (float*)(R1 + 20971520);                    // 2,097,152
  // Region 2: kv GEMM outputs (softmaxed k + v, bf16)
  char* R2 = ws + 100663296;
  ushort_t* ks3 = (ushort_t*)R2;
  ushort_t* v3b = (ushort_t*)(R2 + 8388608);
  ushort_t* ks4 = (ushort_t*)(R2 + 16777216);
  ushort_t* v4b = (ushort_t*)(R2 + 18874368);
  // Region 3: weights bf16, Mt, Z, bqcat
  char* R3 = ws + 121634816;
  ushort_t* WqB = (ushort_t*)R3;                           // 1,048,576
  ushort_t* Wk1B = (ushort_t*)(R3 + 1048576);
  ushort_t* Wv1B = (ushort_t*)(R3 + 1572864);
  ushort_t* Wk2B = (ushort_t*)(R3 + 2097152);
  ushort_t* Wv2B = (ushort_t*)(R3 + 2621440);
  ushort_t* Mt = (ushort_t*)(R3 + 3145728);                // 8,388,608
  float* Z = (float*)(R3 + 11534336);                      // 32,768
  float* bqc = (float*)(R3 + 11567104);                    // 4,096

  // ---- prep1: f2p, weights->bf16, bqc, Z=0 ----
  prep1_kernel<<<17921, 256, 0, stream>>>(f2, f2pe, Wq1, Wq2, Wk1, Wv1, Wk2, Wv2,
                                          bq1, bq2, f2p, WqB, Wk1B, Wv1B, Wk2B,
                                          Wv2B, bqc, Z);

  // ---- G1: E = exp(f2p @ WqB^T + bqc), Z colsums. 256^2 8-wave pipeline ----
  gemm256<8, 0><<<512, 512, 131072, stream>>>(f2p, WqB, bqc, E, Z);

  // ---- prep2: kv inputs (single pass) + ctx zero ----
  prep2_kernel<<<5632, 256, 0, stream>>>(f3, f3pe, f4, f4pe, f3p, f3b, f4p, f4b, ctx);

  // ---- all four kv GEMMs in one launch, k-softmax fused ----
  kv_quad<<<640, 256, 0, stream>>>(f3p, f3b, f4p, f4b,
                                   Wk1B, Wv1B, Wk2B, Wv2B,
                                   bk1, bv1, bk2, bv2,
                                   ks3, v3b, ks4, v4b);

  // ---- ctx = ks^T v  per (b,h), chunked over n with atomic accumulation ----
  ctx_kernel<<<256, 256, 0, stream>>>(ks3, v3b, ctx, 1024, 4);
  ctx_kernel<<<64, 256, 0, stream>>>(ks4, v4b, ctx + 262144, 256, 1);

  // ---- fold ctx, Wr, 1/Z into per-batch Mt[b][j][c] ----
  fold_kernel<<<1024, 256, 0, stream>>>(ctx, Wr, Z, Mt);

  // ---- G2: out = E @ Mt^T + br. 256^2 8-wave pipeline, per-batch Bt ----
  gemm256<16, 2><<<256, 512, 131072, stream>>>(E, Mt, br, (float*)d_out, nullptr);
}

// Round 7
// 220.555 us; speedup vs baseline: 1.0557x; 1.0557x over previous
//
#include <hip/hip_runtime.h>

typedef unsigned short ushort_t;
typedef unsigned int uint32;
typedef __attribute__((ext_vector_type(8))) short short8;
typedef __attribute__((ext_vector_type(4))) float f32x4;

static __device__ __forceinline__ ushort_t f2bf(float f) {
  uint32 u = __builtin_bit_cast(uint32, f);
  u += 0x7fffu + ((u >> 16) & 1u);   // round-to-nearest-even
  return (ushort_t)(u >> 16);
}

static __device__ __forceinline__ void gload_lds16(const ushort_t* g, ushort_t* l) {
  __builtin_amdgcn_global_load_lds(
      (const __attribute__((address_space(1))) uint32*)g,
      (__attribute__((address_space(3))) uint32*)l, 16, 0, 0);
}

static __device__ __forceinline__ void addcvt4(const float* __restrict__ a,
                                               const float* __restrict__ b,
                                               ushort_t* __restrict__ o, int i) {
  float4 va = reinterpret_cast<const float4*>(a)[i];
  if (b != nullptr) {
    float4 vb = reinterpret_cast<const float4*>(b)[i];
    va.x += vb.x; va.y += vb.y; va.z += vb.z; va.w += vb.w;
  }
  ushort4 u;
  u.x = f2bf(va.x); u.y = f2bf(va.y); u.z = f2bf(va.z); u.w = f2bf(va.w);
  reinterpret_cast<ushort4*>(o)[i] = u;
}

// ---------------------------------------------------------------------------
// prepA (runs FIRST): kv inputs (single pass per source), all weights fp32->bf16,
// bqc concat, Z zero, ctx zero. grid = 7169.
// ---------------------------------------------------------------------------
__global__ void prepA_kernel(const float* __restrict__ f3, const float* __restrict__ f3pe,
                             const float* __restrict__ f4, const float* __restrict__ f4pe,
                             const float* __restrict__ Wq1, const float* __restrict__ Wq2,
                             const float* __restrict__ Wk1, const float* __restrict__ Wv1,
                             const float* __restrict__ Wk2, const float* __restrict__ Wv2,
                             const float* __restrict__ bq1, const float* __restrict__ bq2,
                             ushort_t* __restrict__ f3p, ushort_t* __restrict__ f3b,
                             ushort_t* __restrict__ f4p, ushort_t* __restrict__ f4b,
                             ushort_t* __restrict__ WqB, ushort_t* __restrict__ Wk1B,
                             ushort_t* __restrict__ Wv1B, ushort_t* __restrict__ Wk2B,
                             ushort_t* __restrict__ Wv2B, float* __restrict__ bqc,
                             float* __restrict__ Z, float* __restrict__ ctx) {
  int b = blockIdx.x, t = threadIdx.x;
  if (b < 4096) {
    int i = b * 256 + t;
    float4 va = reinterpret_cast<const float4*>(f3)[i];
    float4 vp = reinterpret_cast<const float4*>(f3pe)[i];
    ushort4 ub, up;
    ub.x = f2bf(va.x); ub.y = f2bf(va.y); ub.z = f2bf(va.z); ub.w = f2bf(va.w);
    up.x = f2bf(va.x + vp.x); up.y = f2bf(va.y + vp.y);
    up.z = f2bf(va.z + vp.z); up.w = f2bf(va.w + vp.w);
    reinterpret_cast<ushort4*>(f3b)[i] = ub;
    reinterpret_cast<ushort4*>(f3p)[i] = up;
  } else if (b < 5120) {
    int i = (b - 4096) * 256 + t;
    float4 va = reinterpret_cast<const float4*>(f4)[i];
    float4 vp = reinterpret_cast<const float4*>(f4pe)[i];
    ushort4 ub, up;
    ub.x = f2bf(va.x); ub.y = f2bf(va.y); ub.z = f2bf(va.z); ub.w = f2bf(va.w);
    up.x = f2bf(va.x + vp.x); up.y = f2bf(va.y + vp.y);
    up.z = f2bf(va.z + vp.z); up.w = f2bf(va.w + vp.w);
    reinterpret_cast<ushort4*>(f4b)[i] = ub;
    reinterpret_cast<ushort4*>(f4p)[i] = up;
  } else if (b < 6656) {
    int u = b - 5120;
    int arr = u >> 8, i = (u & 255) * 256 + t;
    const float* s; ushort_t* d;
    switch (arr) {
      case 0: s = Wq1; d = WqB; break;
      case 1: s = Wq2; d = WqB + 262144; break;
      case 2: s = Wk1; d = Wk1B; break;
      case 3: s = Wv1; d = Wv1B; break;
      case 4: s = Wk2; d = Wk2B; break;
      default: s = Wv2; d = Wv2B; break;
    }
    addcvt4(s, nullptr, d, i);
  } else if (b < 7168) {
    reinterpret_cast<float4*>(ctx)[(b - 6656) * 256 + t] = make_float4(0.f, 0.f, 0.f, 0.f);
  } else {
    for (int i = t; i < 512; i += 256) { bqc[i] = bq1[i]; bqc[512 + i] = bq2[i]; }
    for (int i = t; i < 8192; i += 256) Z[i] = 0.f;
  }
}

// ---------------------------------------------------------------------------
// prepB: f2p = bf16(f2+f2pe). grid = 16384. Runs right before G1 (f3* dead).
// ---------------------------------------------------------------------------
__global__ void prepB_kernel(const float* __restrict__ f2, const float* __restrict__ f2pe,
                             ushort_t* __restrict__ f2p) {
  addcvt4(f2, f2pe, f2p, blockIdx.x * 256 + threadIdx.x);
}

// ---------------------------------------------------------------------------
// Shared GEMM core: 128x128 tile, 4 waves, BK=64, global_load_lds staging.
// LDS: row-major 128 x 128B, XOR-swizzle byte ^= ((row&7)<<4).
// gload_lds writes lane-linear, so the global SOURCE is inverse-swizzled.
// ---------------------------------------------------------------------------
static __device__ __forceinline__ void gemm_core(
    const ushort_t* __restrict__ A, const ushort_t* __restrict__ Bt,
    int K, int mBase, int nBase, ushort_t* As, ushort_t* Bs, f32x4 acc[4][4]) {
  const int t = threadIdx.x;
  const int w = t >> 6, l = t & 63;
  const int l15 = l & 15, l4 = l >> 4;
  const int rowInSeg = l >> 3;
  const int srcOff = ((l & 7) ^ rowInSeg) << 3;
  const int wm = (w >> 1) * 64, wn = (w & 1) * 64;

  for (int k0 = 0; k0 < K; k0 += 64) {
#pragma unroll
    for (int i = 0; i < 4; i++) {
      int seg = w * 4 + i;
      int row = seg * 8 + rowInSeg;
      gload_lds16(A + (size_t)(mBase + row) * K + k0 + srcOff, As + seg * 512);
      gload_lds16(Bt + (size_t)(nBase + row) * K + k0 + srcOff, Bs + seg * 512);
    }
    __syncthreads();
#pragma unroll
    for (int kk = 0; kk < 2; kk++) {
      short8 af[4], bfr[4];
      const int kb = kk * 64 + l4 * 16;
#pragma unroll
      for (int f = 0; f < 4; f++) {
        int rowA = wm + f * 16 + l15;
        af[f] = *reinterpret_cast<const short8*>(
            reinterpret_cast<const char*>(As) + rowA * 128 + (kb ^ ((rowA & 7) << 4)));
        int rowB = wn + f * 16 + l15;
        bfr[f] = *reinterpret_cast<const short8*>(
            reinterpret_cast<const char*>(Bs) + rowB * 128 + (kb ^ ((rowB & 7) << 4)));
      }
#pragma unroll
      for (int fm = 0; fm < 4; fm++)
#pragma unroll
        for (int fn = 0; fn < 4; fn++)
          acc[fm][fn] = __builtin_amdgcn_mfma_f32_16x16x32_bf16(af[fm], bfr[fn], acc[fm][fn], 0, 0, 0);
    }
    __syncthreads();
  }
}

// ---------------------------------------------------------------------------
// G1: E = exp(f2p @ WqB^T + bqc) -> bf16, column sums into Z.
// grid 2048 = 256 m-tiles x 8 n-tiles, XCD-chunked swizzle.
// Epilogue: fn INNER so each row's 128B completes in 4 consecutive stores.
// ---------------------------------------------------------------------------
__global__ __launch_bounds__(256, 4)
void gemm_g1(const ushort_t* __restrict__ A, const ushort_t* __restrict__ Bt,
             const float* __restrict__ bias, ushort_t* __restrict__ E,
             float* __restrict__ Z) {
  __shared__ ushort_t As[8192], Bs[8192];
  const int bid = blockIdx.x;
  const int swz = (bid & 7) * 256 + (bid >> 3);
  const int mBase = (swz >> 3) * 128, nBase = (swz & 7) * 128;
  const int t = threadIdx.x, w = t >> 6, lane = t & 63;
  const int l15 = lane & 15, l4 = lane >> 4;
  const int wm = (w >> 1) * 64, wn = (w & 1) * 64;

  f32x4 acc[4][4];
#pragma unroll
  for (int i = 0; i < 4; i++)
#pragma unroll
    for (int j = 0; j < 4; j++) acc[i][j] = (f32x4){0.f, 0.f, 0.f, 0.f};

  gemm_core(A, Bt, 512, mBase, nBase, As, Bs, acc);

  const int N = 1024;
  float bcol[4], csum[4] = {0.f, 0.f, 0.f, 0.f};
#pragma unroll
  for (int fn = 0; fn < 4; fn++) bcol[fn] = bias[nBase + wn + fn * 16 + l15];
#pragma unroll
  for (int fm = 0; fm < 4; fm++) {
#pragma unroll
    for (int r = 0; r < 4; r++) {
      int row = mBase + wm + fm * 16 + l4 * 4 + r;
      float ex[4];
#pragma unroll
      for (int fn = 0; fn < 4; fn++) {
        ex[fn] = __expf(acc[fm][fn][r] + bcol[fn]);
        csum[fn] += ex[fn];
      }
#pragma unroll
      for (int fn = 0; fn < 4; fn++)
        E[(size_t)row * N + nBase + wn + fn * 16 + l15] = f2bf(ex[fn]);
    }
  }
#pragma unroll
  for (int fn = 0; fn < 4; fn++) {
    float s = csum[fn];
    s += __shfl_xor(s, 16);
    s += __shfl_xor(s, 32);
    if (l4 == 0) atomicAdd(&Z[(mBase >> 12) * 1024 + nBase + wn + fn * 16 + l15], s);
  }
}

// ---------------------------------------------------------------------------
// KV quad: all four kv GEMMs (N=512, K=512) in one 640-block launch,
// k-softmax fused in epilogue. XCD-chunked swizzle.
// ---------------------------------------------------------------------------
__global__ __launch_bounds__(256, 4)
void kv_quad(const ushort_t* __restrict__ f3p, const ushort_t* __restrict__ f3b,
             const ushort_t* __restrict__ f4p, const ushort_t* __restrict__ f4b,
             const ushort_t* __restrict__ Wk1B, const ushort_t* __restrict__ Wv1B,
             const ushort_t* __restrict__ Wk2B, const ushort_t* __restrict__ Wv2B,
             const float* __restrict__ bk1, const float* __restrict__ bv1,
             const float* __restrict__ bk2, const float* __restrict__ bv2,
             ushort_t* __restrict__ ks3, ushort_t* __restrict__ v3,
             ushort_t* __restrict__ ks4, ushort_t* __restrict__ v4) {
  __shared__ ushort_t As[8192], Bs[8192];
  const int bid = blockIdx.x;
  const int id = (bid & 7) * 80 + (bid >> 3);
  const ushort_t* A; const ushort_t* Bt; const float* bias; ushort_t* out;
  bool doSM; int loc;
  if (id < 256)      { A = f3p; Bt = Wk1B; bias = bk1; out = ks3; doSM = true;  loc = id; }
  else if (id < 512) { A = f3b; Bt = Wv1B; bias = bv1; out = v3;  doSM = false; loc = id - 256; }
  else if (id < 576) { A = f4p; Bt = Wk2B; bias = bk2; out = ks4; doSM = true;  loc = id - 512; }
  else               { A = f4b; Bt = Wv2B; bias = bv2; out = v4;  doSM = false; loc = id - 576; }
  const int nBase = (loc & 3) * 128, mBase = (loc >> 2) * 128;
  const int t = threadIdx.x, w = t >> 6, lane = t & 63;
  const int l15 = lane & 15, l4 = lane >> 4;
  const int wm = (w >> 1) * 64, wn = (w & 1) * 64;

  f32x4 acc[4][4];
#pragma unroll
  for (int i = 0; i < 4; i++)
#pragma unroll
    for (int j = 0; j < 4; j++) acc[i][j] = (f32x4){0.f, 0.f, 0.f, 0.f};

  gemm_core(A, Bt, 512, mBase, nBase, As, Bs, acc);

  const int N = 512;
  float bcol[4];
#pragma unroll
  for (int fn = 0; fn < 4; fn++) bcol[fn] = bias[nBase + wn + fn * 16 + l15];

  if (doSM) {
#pragma unroll
    for (int fm = 0; fm < 4; fm++) {
#pragma unroll
      for (int r = 0; r < 4; r++) {
        float x[4], m = -1e30f;
#pragma unroll
        for (int fn = 0; fn < 4; fn++) { x[fn] = acc[fm][fn][r] + bcol[fn]; m = fmaxf(m, x[fn]); }
        m = fmaxf(m, __shfl_xor(m, 1));
        m = fmaxf(m, __shfl_xor(m, 2));
        m = fmaxf(m, __shfl_xor(m, 4));
        m = fmaxf(m, __shfl_xor(m, 8));
        float s = 0.f;
#pragma unroll
        for (int fn = 0; fn < 4; fn++) { x[fn] = __expf(x[fn] - m); s += x[fn]; }
        s += __shfl_xor(s, 1);
        s += __shfl_xor(s, 2);
        s += __shfl_xor(s, 4);
        s += __shfl_xor(s, 8);
        float inv = 1.f / s;
        int row = mBase + wm + fm * 16 + l4 * 4 + r;
#pragma unroll
        for (int fn = 0; fn < 4; fn++)
          out[(size_t)row * N + nBase + wn + fn * 16 + l15] = f2bf(x[fn] * inv);
      }
    }
  } else {
#pragma unroll
    for (int fm = 0; fm < 4; fm++) {
#pragma unroll
      for (int r = 0; r < 4; r++) {
        int row = mBase + wm + fm * 16 + l4 * 4 + r;
#pragma unroll
        for (int fn = 0; fn < 4; fn++)
          out[(size_t)row * N + nBase + wn + fn * 16 + l15] =
              f2bf(acc[fm][fn][r] + bcol[fn]);
      }
    }
  }
}

// ---------------------------------------------------------------------------
// G2: out_fp32 = E @ Mt(batch)^T + br.  grid 1024 = 256 m x 4 n, XCD swizzle.
// Epilogue: fn INNER -> 4 consecutive 64B stores per row.
// ---------------------------------------------------------------------------
__global__ __launch_bounds__(256, 4)
void gemm_g2(const ushort_t* __restrict__ E, const ushort_t* __restrict__ Mt,
             const float* __restrict__ bias, float* __restrict__ C) {
  __shared__ ushort_t As[8192], Bs[8192];
  const int bid = blockIdx.x;
  const int swz = (bid & 7) * 128 + (bid >> 3);
  const int tx = swz & 3, ty = swz >> 2;
  const int mBase = ty * 128, nBase = tx * 128;
  const ushort_t* Btb = Mt + (size_t)(ty >> 5) * 524288;
  const int t = threadIdx.x, w = t >> 6, lane = t & 63;
  const int l15 = lane & 15, l4 = lane >> 4;
  const int wm = (w >> 1) * 64, wn = (w & 1) * 64;

  f32x4 acc[4][4];
#pragma unroll
  for (int i = 0; i < 4; i++)
#pragma unroll
    for (int j = 0; j < 4; j++) acc[i][j] = (f32x4){0.f, 0.f, 0.f, 0.f};

  gemm_core(E, Btb, 1024, mBase, nBase, As, Bs, acc);

  const int N = 512;
  float bcol[4];
#pragma unroll
  for (int fn = 0; fn < 4; fn++) bcol[fn] = bias[nBase + wn + fn * 16 + l15];
#pragma unroll
  for (int fm = 0; fm < 4; fm++) {
#pragma unroll
    for (int r = 0; r < 4; r++) {
      int row = mBase + wm + fm * 16 + l4 * 4 + r;
#pragma unroll
      for (int fn = 0; fn < 4; fn++)
        C[(size_t)row * N + nBase + wn + fn * 16 + l15] = acc[fm][fn][r] + bcol[fn];
    }
  }
}

// ---------------------------------------------------------------------------
// ctx[bh,d,e] += sum_{n in chunk} ks[b,n,h*64+d] * v[b,n,h*64+e]
// ---------------------------------------------------------------------------
__global__ __launch_bounds__(256)
void ctx_kernel(const ushort_t* __restrict__ ks, const ushort_t* __restrict__ v,
                float* __restrict__ ctxOut, int Nk, int nChunks) {
  __shared__ float ks_s[64][68];
  __shared__ float v_s[64][68];
  int bh = blockIdx.x / nChunks;
  int chunk = blockIdx.x - bh * nChunks;
  int b = bh >> 3, h = bh & 7;
  int t = threadIdx.x;
  int td = t & 15, te = t >> 4;
  float acc[4][4] = {};
  size_t rowBase = (size_t)b * Nk + chunk * 256;
  for (int n0 = 0; n0 < 256; n0 += 64) {
#pragma unroll
    for (int i = 0; i < 16; i++) {
      int idx = i * 256 + t;
      int n = idx >> 6, d = idx & 63;
      size_t g = (rowBase + n0 + n) * 512 + h * 64 + d;
      ks_s[n][d] = __builtin_bit_cast(float, (uint32)ks[g] << 16);
      v_s[n][d] = __builtin_bit_cast(float, (uint32)v[g] << 16);
    }
    __syncthreads();
#pragma unroll 8
    for (int n = 0; n < 64; n++) {
      float4 cv = *reinterpret_cast<const float4*>(&ks_s[n][td * 4]);
      float4 vv = *reinterpret_cast<const float4*>(&v_s[n][te * 4]);
      float ca[4] = {cv.x, cv.y, cv.z, cv.w};
      float va[4] = {vv.x, vv.y, vv.z, vv.w};
#pragma unroll
      for (int i = 0; i < 4; i++)
#pragma unroll
        for (int j = 0; j < 4; j++) acc[i][j] += ca[i] * va[j];
    }
    __syncthreads();
  }
  float* dst = ctxOut + (size_t)bh * 4096;
#pragma unroll
  for (int i = 0; i < 4; i++)
#pragma unroll
    for (int j = 0; j < 4; j++)
      atomicAdd(&dst[(td * 4 + i) * 64 + te * 4 + j], acc[i][j]);
}

// ---------------------------------------------------------------------------
// Fold: Mt[b][j][c] = (sum_e ctx[branch,b,h,d,e]*Wr[j, branch*512+h*64+e]) / Z[b,c]
// ---------------------------------------------------------------------------
__global__ __launch_bounds__(256)
void fold_kernel(const float* __restrict__ ctx, const float* __restrict__ Wr,
                 const float* __restrict__ Z, ushort_t* __restrict__ Mt) {
  __shared__ float ctxT[64][68];   // [e][d]
  __shared__ float wrT[64][68];    // [e][jl]
  __shared__ float zinv[64];
  int blk = blockIdx.x;
  int jc = blk & 7;
  int h = (blk >> 3) & 7;
  int branch = (blk >> 6) & 1;
  int b = blk >> 7;
  int t = threadIdx.x;
  int cbase = branch * 512 + h * 64;
  const float* csrc = ctx + (size_t)(branch * 64 + b * 8 + h) * 4096;
#pragma unroll
  for (int i = 0; i < 16; i++) {
    int idx = i * 256 + t;
    int d = idx >> 6, e = idx & 63;
    ctxT[e][d] = csrc[d * 64 + e];
  }
#pragma unroll
  for (int i = 0; i < 16; i++) {
    int idx = i * 256 + t;
    int jl = idx >> 6, e = idx & 63;
    wrT[e][jl] = Wr[(size_t)(jc * 64 + jl) * 1024 + cbase + e];
  }
  if (t < 64) zinv[t] = 1.0f / Z[b * 1024 + cbase + t];
  __syncthreads();
  int td = t & 15, tj = t >> 4;
  float acc[4][4] = {};   // [d_i][jj]
#pragma unroll 8
  for (int e = 0; e < 64; e++) {
    float4 cv = *reinterpret_cast<const float4*>(&ctxT[e][td * 4]);
    float4 wv = *reinterpret_cast<const float4*>(&wrT[e][tj * 4]);
    float ca[4] = {cv.x, cv.y, cv.z, cv.w};
    float wa[4] = {wv.x, wv.y, wv.z, wv.w};
#pragma unroll
    for (int i = 0; i < 4; i++)
#pragma unroll
      for (int jj = 0; jj < 4; jj++) acc[i][jj] += ca[i] * wa[jj];
  }
  float zi[4] = {zinv[td * 4], zinv[td * 4 + 1], zinv[td * 4 + 2], zinv[td * 4 + 3]};
#pragma unroll
  for (int jj = 0; jj < 4; jj++) {
    ushort4 u;
    u.x = f2bf(acc[0][jj] * zi[0]);
    u.y = f2bf(acc[1][jj] * zi[1]);
    u.z = f2bf(acc[2][jj] * zi[2]);
    u.w = f2bf(acc[3][jj] * zi[3]);
    *reinterpret_cast<ushort4*>(
        &Mt[(size_t)(b * 512 + jc * 64 + tj * 4 + jj) * 1024 + cbase + td * 4]) = u;
  }
}

// ---------------------------------------------------------------------------
extern "C" void kernel_launch(void* const* d_in, const int* in_sizes, int n_in,
                              void* d_out, int out_size, void* d_ws, size_t ws_size,
                              hipStream_t stream) {
  const float* f2 = (const float*)d_in[0];
  const float* f3 = (const float*)d_in[1];
  const float* f4 = (const float*)d_in[2];
  const float* f2pe = (const float*)d_in[3];
  const float* f3pe = (const float*)d_in[4];
  const float* f4pe = (const float*)d_in[5];
  const float* Wq1 = (const float*)d_in[6];
  const float* bq1 = (const float*)d_in[7];
  const float* Wk1 = (const float*)d_in[8];
  const float* bk1 = (const float*)d_in[9];
  const float* Wv1 = (const float*)d_in[10];
  const float* bv1 = (const float*)d_in[11];
  const float* Wq2 = (const float*)d_in[12];
  const float* bq2 = (const float*)d_in[13];
  const float* Wk2 = (const float*)d_in[14];
  const float* bk2 = (const float*)d_in[15];
  const float* Wv2 = (const float*)d_in[16];
  const float* bv2 = (const float*)d_in[17];
  const float* Wr = (const float*)d_in[18];
  const float* br = (const float*)d_in[19];

  char* ws = (char*)d_ws;
  // Region 0: E bf16 [32768,1024]
  ushort_t* E = (ushort_t*)(ws + 0);                       // 67,108,864 B
  // Region 1 (33.5 MB): kv inputs early, then f2p (f3* dead after kv_quad)
  char* R1 = ws + 67108864;
  ushort_t* f3p = (ushort_t*)R1;                           // 8,388,608
  ushort_t* f3b = (ushort_t*)(R1 + 8388608);               // 8,388,608
  ushort_t* f4p = (ushort_t*)(R1 + 16777216);              // 2,097,152
  ushort_t* f4b = (ushort_t*)(R1 + 18874368);              // 2,097,152
  ushort_t* f2p = (ushort_t*)R1;                           // 33,554,432 (later)
  // Region 2: kv GEMM outputs (softmaxed k + v, bf16)
  char* R2 = ws + 100663296;
  ushort_t* ks3 = (ushort_t*)R2;
  ushort_t* v3b = (ushort_t*)(R2 + 8388608);
  ushort_t* ks4 = (ushort_t*)(R2 + 16777216);
  ushort_t* v4b = (ushort_t*)(R2 + 18874368);
  // Region 3: weights bf16, Mt, Z, bqc, ctx (ctx OUTSIDE R1 — survives f2p)
  char* R3 = ws + 121634816;
  ushort_t* WqB = (ushort_t*)R3;                           // 1,048,576
  ushort_t* Wk1B = (ushort_t*)(R3 + 1048576);
  ushort_t* Wv1B = (ushort_t*)(R3 + 1572864);
  ushort_t* Wk2B = (ushort_t*)(R3 + 2097152);
  ushort_t* Wv2B = (ushort_t*)(R3 + 2621440);
  ushort_t* Mt = (ushort_t*)(R3 + 3145728);                // 8,388,608
  float* Z = (float*)(R3 + 11534336);                      // 32,768
  float* bqc = (float*)(R3 + 11567104);                    // 4,096
  float* ctx = (float*)(R3 + 11571200);                    // 2,097,152

  // ---- prepA: kv inputs, weights->bf16, bqc, Z=0, ctx=0 ----
  prepA_kernel<<<7169, 256, 0, stream>>>(f3, f3pe, f4, f4pe,
                                         Wq1, Wq2, Wk1, Wv1, Wk2, Wv2, bq1, bq2,
                                         f3p, f3b, f4p, f4b,
                                         WqB, Wk1B, Wv1B, Wk2B, Wv2B, bqc, Z, ctx);

  // ---- all four kv GEMMs in one launch, k-softmax fused ----
  kv_quad<<<640, 256, 0, stream>>>(f3p, f3b, f4p, f4b,
                                   Wk1B, Wv1B, Wk2B, Wv2B,
                                   bk1, bv1, bk2, bv2,
                                   ks3, v3b, ks4, v4b);

  // ---- ctx = ks^T v  per (b,h), chunked over n with atomic accumulation ----
  ctx_kernel<<<256, 256, 0, stream>>>(ks3, v3b, ctx, 1024, 4);
  ctx_kernel<<<64, 256, 0, stream>>>(ks4, v4b, ctx + 262144, 256, 1);

  // ---- prepB: f2p (overwrites dead kv inputs) ----
  prepB_kernel<<<16384, 256, 0, stream>>>(f2, f2pe, f2p);

  // ---- G1: E = exp(f2p @ WqB^T + bqc), Z colsums ----
  gemm_g1<<<2048, 256, 0, stream>>>(f2p, WqB, bqc, E, Z);

  // ---- fold ctx, Wr, 1/Z into per-batch Mt[b][j][c] ----
  fold_kernel<<<1024, 256, 0, stream>>>(ctx, Wr, Z, Mt);

  // ---- G2: out = E @ Mt^T + br (E still L3-hot from G1) ----
  gemm_g2<<<1024, 256, 0, stream>>>(E, Mt, br, (float*)d_out);
}

// Round 8
// 181.568 us; speedup vs baseline: 1.2824x; 1.2147x over previous
//
#include <hip/hip_runtime.h>

typedef unsigned short ushort_t;
typedef unsigned int uint32;
typedef __attribute__((ext_vector_type(8))) short short8;
typedef __attribute__((ext_vector_type(4))) float f32x4;

static __device__ __forceinline__ ushort_t f2bf(float f) {
  uint32 u = __builtin_bit_cast(uint32, f);
  u += 0x7fffu + ((u >> 16) & 1u);   // round-to-nearest-even
  return (ushort_t)(u >> 16);
}

static __device__ __forceinline__ void gload_lds16(const ushort_t* g, ushort_t* l) {
  __builtin_amdgcn_global_load_lds(
      (const __attribute__((address_space(1))) uint32*)g,
      (__attribute__((address_space(3))) uint32*)l, 16, 0, 0);
}

static __device__ __forceinline__ void addcvt4(const float* __restrict__ a,
                                               const float* __restrict__ b,
                                               ushort_t* __restrict__ o, int i) {
  float4 va = reinterpret_cast<const float4*>(a)[i];
  if (b != nullptr) {
    float4 vb = reinterpret_cast<const float4*>(b)[i];
    va.x += vb.x; va.y += vb.y; va.z += vb.z; va.w += vb.w;
  }
  ushort4 u;
  u.x = f2bf(va.x); u.y = f2bf(va.y); u.z = f2bf(va.z); u.w = f2bf(va.w);
  reinterpret_cast<ushort4*>(o)[i] = u;
}

// ---------------------------------------------------------------------------
// prepA (runs FIRST): kv inputs (single pass per source), all weights fp32->bf16,
// bqc concat, Z zero, ctx zero. grid = 7169.
// ---------------------------------------------------------------------------
__global__ void prepA_kernel(const float* __restrict__ f3, const float* __restrict__ f3pe,
                             const float* __restrict__ f4, const float* __restrict__ f4pe,
                             const float* __restrict__ Wq1, const float* __restrict__ Wq2,
                             const float* __restrict__ Wk1, const float* __restrict__ Wv1,
                             const float* __restrict__ Wk2, const float* __restrict__ Wv2,
                             const float* __restrict__ bq1, const float* __restrict__ bq2,
                             ushort_t* __restrict__ f3p, ushort_t* __restrict__ f3b,
                             ushort_t* __restrict__ f4p, ushort_t* __restrict__ f4b,
                             ushort_t* __restrict__ WqB, ushort_t* __restrict__ Wk1B,
                             ushort_t* __restrict__ Wv1B, ushort_t* __restrict__ Wk2B,
                             ushort_t* __restrict__ Wv2B, float* __restrict__ bqc,
                             float* __restrict__ Z, float* __restrict__ ctx) {
  int b = blockIdx.x, t = threadIdx.x;
  if (b < 4096) {
    int i = b * 256 + t;
    float4 va = reinterpret_cast<const float4*>(f3)[i];
    float4 vp = reinterpret_cast<const float4*>(f3pe)[i];
    ushort4 ub, up;
    ub.x = f2bf(va.x); ub.y = f2bf(va.y); ub.z = f2bf(va.z); ub.w = f2bf(va.w);
    up.x = f2bf(va.x + vp.x); up.y = f2bf(va.y + vp.y);
    up.z = f2bf(va.z + vp.z); up.w = f2bf(va.w + vp.w);
    reinterpret_cast<ushort4*>(f3b)[i] = ub;
    reinterpret_cast<ushort4*>(f3p)[i] = up;
  } else if (b < 5120) {
    int i = (b - 4096) * 256 + t;
    float4 va = reinterpret_cast<const float4*>(f4)[i];
    float4 vp = reinterpret_cast<const float4*>(f4pe)[i];
    ushort4 ub, up;
    ub.x = f2bf(va.x); ub.y = f2bf(va.y); ub.z = f2bf(va.z); ub.w = f2bf(va.w);
    up.x = f2bf(va.x + vp.x); up.y = f2bf(va.y + vp.y);
    up.z = f2bf(va.z + vp.z); up.w = f2bf(va.w + vp.w);
    reinterpret_cast<ushort4*>(f4b)[i] = ub;
    reinterpret_cast<ushort4*>(f4p)[i] = up;
  } else if (b < 6656) {
    int u = b - 5120;
    int arr = u >> 8, i = (u & 255) * 256 + t;
    const float* s; ushort_t* d;
    switch (arr) {
      case 0: s = Wq1; d = WqB; break;
      case 1: s = Wq2; d = WqB + 262144; break;
      case 2: s = Wk1; d = Wk1B; break;
      case 3: s = Wv1; d = Wv1B; break;
      case 4: s = Wk2; d = Wk2B; break;
      default: s = Wv2; d = Wv2B; break;
    }
    addcvt4(s, nullptr, d, i);
  } else if (b < 7168) {
    reinterpret_cast<float4*>(ctx)[(b - 6656) * 256 + t] = make_float4(0.f, 0.f, 0.f, 0.f);
  } else {
    for (int i = t; i < 512; i += 256) { bqc[i] = bq1[i]; bqc[512 + i] = bq2[i]; }
    for (int i = t; i < 8192; i += 256) Z[i] = 0.f;
  }
}

// ---------------------------------------------------------------------------
// ctxprepB (fat kernel): blocks 0..319 compute ctx (LDS/VALU-bound, low HBM);
// blocks 320..4415 stream f2p = bf16(f2+f2pe) at 16 elems/thread — the ctx
// work hides under the stream's HBM time. f2p overwrites dead f3*/f4* space.
// ---------------------------------------------------------------------------
__global__ __launch_bounds__(256)
void ctxprepB_kernel(const ushort_t* __restrict__ ks3, const ushort_t* __restrict__ v3,
                     const ushort_t* __restrict__ ks4, const ushort_t* __restrict__ v4,
                     float* __restrict__ ctxOut,
                     const float* __restrict__ f2, const float* __restrict__ f2pe,
                     ushort_t* __restrict__ f2p) {
  __shared__ float ks_s[64][68];
  __shared__ float v_s[64][68];
  const int b = blockIdx.x, t = threadIdx.x;

  if (b >= 320) {
    // ---- streaming: 4x float4 per stream, contiguous 16KB per block ----
    const float4* A4 = reinterpret_cast<const float4*>(f2);
    const float4* P4 = reinterpret_cast<const float4*>(f2pe);
    uint4* O4 = reinterpret_cast<uint4*>(f2p);
    const int base = (b - 320) * 1024;
#pragma unroll
    for (int j = 0; j < 4; j++) {
      int i = base + j * 256 + t;
      float4 va = A4[i];
      float4 vp = P4[i];
      ushort4 u;
      u.x = f2bf(va.x + vp.x); u.y = f2bf(va.y + vp.y);
      u.z = f2bf(va.z + vp.z); u.w = f2bf(va.w + vp.w);
      reinterpret_cast<ushort4*>(O4)[i] = u;
    }
    return;
  }

  // ---- ctx: [bh,d,e] += sum_n ks[b,n,h*64+d] * v[b,n,h*64+e] ----
  const ushort_t* ks; const ushort_t* v; float* dstBase; int Nk, bh, chunk;
  if (b < 256) { ks = ks3; v = v3; dstBase = ctxOut;          Nk = 1024; bh = b >> 2; chunk = b & 3; }
  else         { ks = ks4; v = v4; dstBase = ctxOut + 262144; Nk = 256;  bh = b - 256; chunk = 0; }
  const int bb = bh >> 3, h = bh & 7;
  const int td = t & 15, te = t >> 4;
  float acc[4][4] = {};
  size_t rowBase = (size_t)bb * Nk + chunk * 256;
  for (int n0 = 0; n0 < 256; n0 += 64) {
#pragma unroll
    for (int i = 0; i < 16; i++) {
      int idx = i * 256 + t;
      int n = idx >> 6, d = idx & 63;
      size_t g = (rowBase + n0 + n) * 512 + h * 64 + d;
      ks_s[n][d] = __builtin_bit_cast(float, (uint32)ks[g] << 16);
      v_s[n][d] = __builtin_bit_cast(float, (uint32)v[g] << 16);
    }
    __syncthreads();
#pragma unroll 8
    for (int n = 0; n < 64; n++) {
      float4 cv = *reinterpret_cast<const float4*>(&ks_s[n][td * 4]);
      float4 vv = *reinterpret_cast<const float4*>(&v_s[n][te * 4]);
      float ca[4] = {cv.x, cv.y, cv.z, cv.w};
      float va[4] = {vv.x, vv.y, vv.z, vv.w};
#pragma unroll
      for (int i = 0; i < 4; i++)
#pragma unroll
        for (int j = 0; j < 4; j++) acc[i][j] += ca[i] * va[j];
    }
    __syncthreads();
  }
  float* dst = dstBase + (size_t)bh * 4096;
#pragma unroll
  for (int i = 0; i < 4; i++)
#pragma unroll
    for (int j = 0; j < 4; j++)
      atomicAdd(&dst[(td * 4 + i) * 64 + te * 4 + j], acc[i][j]);
}

// ---------------------------------------------------------------------------
// Shared GEMM core: 128x128 tile, 4 waves, BK=64, global_load_lds staging.
// LDS: row-major 128 x 128B, XOR-swizzle byte ^= ((row&7)<<4).
// gload_lds writes lane-linear, so the global SOURCE is inverse-swizzled.
// ---------------------------------------------------------------------------
static __device__ __forceinline__ void gemm_core(
    const ushort_t* __restrict__ A, const ushort_t* __restrict__ Bt,
    int K, int mBase, int nBase, ushort_t* As, ushort_t* Bs, f32x4 acc[4][4]) {
  const int t = threadIdx.x;
  const int w = t >> 6, l = t & 63;
  const int l15 = l & 15, l4 = l >> 4;
  const int rowInSeg = l >> 3;
  const int srcOff = ((l & 7) ^ rowInSeg) << 3;
  const int wm = (w >> 1) * 64, wn = (w & 1) * 64;

  for (int k0 = 0; k0 < K; k0 += 64) {
#pragma unroll
    for (int i = 0; i < 4; i++) {
      int seg = w * 4 + i;
      int row = seg * 8 + rowInSeg;
      gload_lds16(A + (size_t)(mBase + row) * K + k0 + srcOff, As + seg * 512);
      gload_lds16(Bt + (size_t)(nBase + row) * K + k0 + srcOff, Bs + seg * 512);
    }
    __syncthreads();
#pragma unroll
    for (int kk = 0; kk < 2; kk++) {
      short8 af[4], bfr[4];
      const int kb = kk * 64 + l4 * 16;
#pragma unroll
      for (int f = 0; f < 4; f++) {
        int rowA = wm + f * 16 + l15;
        af[f] = *reinterpret_cast<const short8*>(
            reinterpret_cast<const char*>(As) + rowA * 128 + (kb ^ ((rowA & 7) << 4)));
        int rowB = wn + f * 16 + l15;
        bfr[f] = *reinterpret_cast<const short8*>(
            reinterpret_cast<const char*>(Bs) + rowB * 128 + (kb ^ ((rowB & 7) << 4)));
      }
#pragma unroll
      for (int fm = 0; fm < 4; fm++)
#pragma unroll
        for (int fn = 0; fn < 4; fn++)
          acc[fm][fn] = __builtin_amdgcn_mfma_f32_16x16x32_bf16(af[fm], bfr[fn], acc[fm][fn], 0, 0, 0);
    }
    __syncthreads();
  }
}

// ---------------------------------------------------------------------------
// G1: E = exp(f2p @ WqB^T + bqc) -> bf16, column sums into Z.
// grid 2048 = 256 m-tiles x 8 n-tiles, XCD-chunked swizzle.
// Epilogue: fn INNER so each row's 128B completes in 4 consecutive stores.
// ---------------------------------------------------------------------------
__global__ __launch_bounds__(256, 4)
void gemm_g1(const ushort_t* __restrict__ A, const ushort_t* __restrict__ Bt,
             const float* __restrict__ bias, ushort_t* __restrict__ E,
             float* __restrict__ Z) {
  __shared__ ushort_t As[8192], Bs[8192];
  const int bid = blockIdx.x;
  const int swz = (bid & 7) * 256 + (bid >> 3);
  const int mBase = (swz >> 3) * 128, nBase = (swz & 7) * 128;
  const int t = threadIdx.x, w = t >> 6, lane = t & 63;
  const int l15 = lane & 15, l4 = lane >> 4;
  const int wm = (w >> 1) * 64, wn = (w & 1) * 64;

  f32x4 acc[4][4];
#pragma unroll
  for (int i = 0; i < 4; i++)
#pragma unroll
    for (int j = 0; j < 4; j++) acc[i][j] = (f32x4){0.f, 0.f, 0.f, 0.f};

  gemm_core(A, Bt, 512, mBase, nBase, As, Bs, acc);

  const int N = 1024;
  float bcol[4], csum[4] = {0.f, 0.f, 0.f, 0.f};
#pragma unroll
  for (int fn = 0; fn < 4; fn++) bcol[fn] = bias[nBase + wn + fn * 16 + l15];
#pragma unroll
  for (int fm = 0; fm < 4; fm++) {
#pragma unroll
    for (int r = 0; r < 4; r++) {
      int row = mBase + wm + fm * 16 + l4 * 4 + r;
      float ex[4];
#pragma unroll
      for (int fn = 0; fn < 4; fn++) {
        ex[fn] = __expf(acc[fm][fn][r] + bcol[fn]);
        csum[fn] += ex[fn];
      }
#pragma unroll
      for (int fn = 0; fn < 4; fn++)
        E[(size_t)row * N + nBase + wn + fn * 16 + l15] = f2bf(ex[fn]);
    }
  }
#pragma unroll
  for (int fn = 0; fn < 4; fn++) {
    float s = csum[fn];
    s += __shfl_xor(s, 16);
    s += __shfl_xor(s, 32);
    if (l4 == 0) atomicAdd(&Z[(mBase >> 12) * 1024 + nBase + wn + fn * 16 + l15], s);
  }
}

// ---------------------------------------------------------------------------
// KV quad: all four kv GEMMs (N=512, K=512) in one 640-block launch,
// k-softmax fused in epilogue. XCD-chunked swizzle.
// ---------------------------------------------------------------------------
__global__ __launch_bounds__(256, 4)
void kv_quad(const ushort_t* __restrict__ f3p, const ushort_t* __restrict__ f3b,
             const ushort_t* __restrict__ f4p, const ushort_t* __restrict__ f4b,
             const ushort_t* __restrict__ Wk1B, const ushort_t* __restrict__ Wv1B,
             const ushort_t* __restrict__ Wk2B, const ushort_t* __restrict__ Wv2B,
             const float* __restrict__ bk1, const float* __restrict__ bv1,
             const float* __restrict__ bk2, const float* __restrict__ bv2,
             ushort_t* __restrict__ ks3, ushort_t* __restrict__ v3,
             ushort_t* __restrict__ ks4, ushort_t* __restrict__ v4) {
  __shared__ ushort_t As[8192], Bs[8192];
  const int bid = blockIdx.x;
  const int id = (bid & 7) * 80 + (bid >> 3);
  const ushort_t* A; const ushort_t* Bt; const float* bias; ushort_t* out;
  bool doSM; int loc;
  if (id < 256)      { A = f3p; Bt = Wk1B; bias = bk1; out = ks3; doSM = true;  loc = id; }
  else if (id < 512) { A = f3b; Bt = Wv1B; bias = bv1; out = v3;  doSM = false; loc = id - 256; }
  else if (id < 576) { A = f4p; Bt = Wk2B; bias = bk2; out = ks4; doSM = true;  loc = id - 512; }
  else               { A = f4b; Bt = Wv2B; bias = bv2; out = v4;  doSM = false; loc = id - 576; }
  const int nBase = (loc & 3) * 128, mBase = (loc >> 2) * 128;
  const int t = threadIdx.x, w = t >> 6, lane = t & 63;
  const int l15 = lane & 15, l4 = lane >> 4;
  const int wm = (w >> 1) * 64, wn = (w & 1) * 64;

  f32x4 acc[4][4];
#pragma unroll
  for (int i = 0; i < 4; i++)
#pragma unroll
    for (int j = 0; j < 4; j++) acc[i][j] = (f32x4){0.f, 0.f, 0.f, 0.f};

  gemm_core(A, Bt, 512, mBase, nBase, As, Bs, acc);

  const int N = 512;
  float bcol[4];
#pragma unroll
  for (int fn = 0; fn < 4; fn++) bcol[fn] = bias[nBase + wn + fn * 16 + l15];

  if (doSM) {
#pragma unroll
    for (int fm = 0; fm < 4; fm++) {
#pragma unroll
      for (int r = 0; r < 4; r++) {
        float x[4], m = -1e30f;
#pragma unroll
        for (int fn = 0; fn < 4; fn++) { x[fn] = acc[fm][fn][r] + bcol[fn]; m = fmaxf(m, x[fn]); }
        m = fmaxf(m, __shfl_xor(m, 1));
        m = fmaxf(m, __shfl_xor(m, 2));
        m = fmaxf(m, __shfl_xor(m, 4));
        m = fmaxf(m, __shfl_xor(m, 8));
        float s = 0.f;
#pragma unroll
        for (int fn = 0; fn < 4; fn++) { x[fn] = __expf(x[fn] - m); s += x[fn]; }
        s += __shfl_xor(s, 1);
        s += __shfl_xor(s, 2);
        s += __shfl_xor(s, 4);
        s += __shfl_xor(s, 8);
        float inv = 1.f / s;
        int row = mBase + wm + fm * 16 + l4 * 4 + r;
#pragma unroll
        for (int fn = 0; fn < 4; fn++)
          out[(size_t)row * N + nBase + wn + fn * 16 + l15] = f2bf(x[fn] * inv);
      }
    }
  } else {
#pragma unroll
    for (int fm = 0; fm < 4; fm++) {
#pragma unroll
      for (int r = 0; r < 4; r++) {
        int row = mBase + wm + fm * 16 + l4 * 4 + r;
#pragma unroll
        for (int fn = 0; fn < 4; fn++)
          out[(size_t)row * N + nBase + wn + fn * 16 + l15] =
              f2bf(acc[fm][fn][r] + bcol[fn]);
      }
    }
  }
}

// ---------------------------------------------------------------------------
// G2: out_fp32 = E @ Mt(batch)^T + br.  grid 1024 = 256 m x 4 n, XCD swizzle.
// Epilogue: fn INNER -> 4 consecutive 64B stores per row.
// ---------------------------------------------------------------------------
__global__ __launch_bounds__(256, 4)
void gemm_g2(const ushort_t* __restrict__ E, const ushort_t* __restrict__ Mt,
             const float* __restrict__ bias, float* __restrict__ C) {
  __shared__ ushort_t As[8192], Bs[8192];
  const int bid = blockIdx.x;
  const int swz = (bid & 7) * 128 + (bid >> 3);
  const int tx = swz & 3, ty = swz >> 2;
  const int mBase = ty * 128, nBase = tx * 128;
  const ushort_t* Btb = Mt + (size_t)(ty >> 5) * 524288;
  const int t = threadIdx.x, w = t >> 6, lane = t & 63;
  const int l15 = lane & 15, l4 = lane >> 4;
  const int wm = (w >> 1) * 64, wn = (w & 1) * 64;

  f32x4 acc[4][4];
#pragma unroll
  for (int i = 0; i < 4; i++)
#pragma unroll
    for (int j = 0; j < 4; j++) acc[i][j] = (f32x4){0.f, 0.f, 0.f, 0.f};

  gemm_core(E, Btb, 1024, mBase, nBase, As, Bs, acc);

  const int N = 512;
  float bcol[4];
#pragma unroll
  for (int fn = 0; fn < 4; fn++) bcol[fn] = bias[nBase + wn + fn * 16 + l15];
#pragma unroll
  for (int fm = 0; fm < 4; fm++) {
#pragma unroll
    for (int r = 0; r < 4; r++) {
      int row = mBase + wm + fm * 16 + l4 * 4 + r;
#pragma unroll
      for (int fn = 0; fn < 4; fn++)
        C[(size_t)row * N + nBase + wn + fn * 16 + l15] = acc[fm][fn][r] + bcol[fn];
    }
  }
}

// ---------------------------------------------------------------------------
// Fold: Mt[b][j][c] = (sum_e ctx[branch,b,h,d,e]*Wr[j, branch*512+h*64+e]) / Z[b,c]
// ---------------------------------------------------------------------------
__global__ __launch_bounds__(256)
void fold_kernel(const float* __restrict__ ctx, const float* __restrict__ Wr,
                 const float* __restrict__ Z, ushort_t* __restrict__ Mt) {
  __shared__ float ctxT[64][68];   // [e][d]
  __shared__ float wrT[64][68];    // [e][jl]
  __shared__ float zinv[64];
  int blk = blockIdx.x;
  int jc = blk & 7;
  int h = (blk >> 3) & 7;
  int branch = (blk >> 6) & 1;
  int b = blk >> 7;
  int t = threadIdx.x;
  int cbase = branch * 512 + h * 64;
  const float* csrc = ctx + (size_t)(branch * 64 + b * 8 + h) * 4096;
#pragma unroll
  for (int i = 0; i < 16; i++) {
    int idx = i * 256 + t;
    int d = idx >> 6, e = idx & 63;
    ctxT[e][d] = csrc[d * 64 + e];
  }
#pragma unroll
  for (int i = 0; i < 16; i++) {
    int idx = i * 256 + t;
    int jl = idx >> 6, e = idx & 63;
    wrT[e][jl] = Wr[(size_t)(jc * 64 + jl) * 1024 + cbase + e];
  }
  if (t < 64) zinv[t] = 1.0f / Z[b * 1024 + cbase + t];
  __syncthreads();
  int td = t & 15, tj = t >> 4;
  float acc[4][4] = {};   // [d_i][jj]
#pragma unroll 8
  for (int e = 0; e < 64; e++) {
    float4 cv = *reinterpret_cast<const float4*>(&ctxT[e][td * 4]);
    float4 wv = *reinterpret_cast<const float4*>(&wrT[e][tj * 4]);
    float ca[4] = {cv.x, cv.y, cv.z, cv.w};
    float wa[4] = {wv.x, wv.y, wv.z, wv.w};
#pragma unroll
    for (int i = 0; i < 4; i++)
#pragma unroll
      for (int jj = 0; jj < 4; jj++) acc[i][jj] += ca[i] * wa[jj];
  }
  float zi[4] = {zinv[td * 4], zinv[td * 4 + 1], zinv[td * 4 + 2], zinv[td * 4 + 3]};
#pragma unroll
  for (int jj = 0; jj < 4; jj++) {
    ushort4 u;
    u.x = f2bf(acc[0][jj] * zi[0]);
    u.y = f2bf(acc[1][jj] * zi[1]);
    u.z = f2bf(acc[2][jj] * zi[2]);
    u.w = f2bf(acc[3][jj] * zi[3]);
    *reinterpret_cast<ushort4*>(
        &Mt[(size_t)(b * 512 + jc * 64 + tj * 4 + jj) * 1024 + cbase + td * 4]) = u;
  }
}

// ---------------------------------------------------------------------------
extern "C" void kernel_launch(void* const* d_in, const int* in_sizes, int n_in,
                              void* d_out, int out_size, void* d_ws, size_t ws_size,
                              hipStream_t stream) {
  const float* f2 = (const float*)d_in[0];
  const float* f3 = (const float*)d_in[1];
  const float* f4 = (const float*)d_in[2];
  const float* f2pe = (const float*)d_in[3];
  const float* f3pe = (const float*)d_in[4];
  const float* f4pe = (const float*)d_in[5];
  const float* Wq1 = (const float*)d_in[6];
  const float* bq1 = (const float*)d_in[7];
  const float* Wk1 = (const float*)d_in[8];
  const float* bk1 = (const float*)d_in[9];
  const float* Wv1 = (const float*)d_in[10];
  const float* bv1 = (const float*)d_in[11];
  const float* Wq2 = (const float*)d_in[12];
  const float* bq2 = (const float*)d_in[13];
  const float* Wk2 = (const float*)d_in[14];
  const float* bk2 = (const float*)d_in[15];
  const float* Wv2 = (const float*)d_in[16];
  const float* bv2 = (const float*)d_in[17];
  const float* Wr = (const float*)d_in[18];
  const float* br = (const float*)d_in[19];

  char* ws = (char*)d_ws;
  // Region 0: E bf16 [32768,1024]
  ushort_t* E = (ushort_t*)(ws + 0);                       // 67,108,864 B
  // Region 1 (33.5 MB): kv inputs early, then f2p (f3* dead after kv_quad)
  char* R1 = ws + 67108864;
  ushort_t* f3p = (ushort_t*)R1;                           // 8,388,608
  ushort_t* f3b = (ushort_t*)(R1 + 8388608);               // 8,388,608
  ushort_t* f4p = (ushort_t*)(R1 + 16777216);              // 2,097,152
  ushort_t* f4b = (ushort_t*)(R1 + 18874368);              // 2,097,152
  ushort_t* f2p = (ushort_t*)R1;                           // 33,554,432 (later)
  // Region 2: kv GEMM outputs (softmaxed k + v, bf16)
  char* R2 = ws + 100663296;
  ushort_t* ks3 = (ushort_t*)R2;
  ushort_t* v3b = (ushort_t*)(R2 + 8388608);
  ushort_t* ks4 = (ushort_t*)(R2 + 16777216);
  ushort_t* v4b = (ushort_t*)(R2 + 18874368);
  // Region 3: weights bf16, Mt, Z, bqc, ctx (ctx OUTSIDE R1 — survives f2p)
  char* R3 = ws + 121634816;
  ushort_t* WqB = (ushort_t*)R3;                           // 1,048,576
  ushort_t* Wk1B = (ushort_t*)(R3 + 1048576);
  ushort_t* Wv1B = (ushort_t*)(R3 + 1572864);
  ushort_t* Wk2B = (ushort_t*)(R3 + 2097152);
  ushort_t* Wv2B = (ushort_t*)(R3 + 2621440);
  ushort_t* Mt = (ushort_t*)(R3 + 3145728);                // 8,388,608
  float* Z = (float*)(R3 + 11534336);                      // 32,768
  float* bqc = (float*)(R3 + 11567104);                    // 4,096
  float* ctx = (float*)(R3 + 11571200);                    // 2,097,152

  // ---- prepA: kv inputs, weights->bf16, bqc, Z=0, ctx=0 ----
  prepA_kernel<<<7169, 256, 0, stream>>>(f3, f3pe, f4, f4pe,
                                         Wq1, Wq2, Wk1, Wv1, Wk2, Wv2, bq1, bq2,
                                         f3p, f3b, f4p, f4b,
                                         WqB, Wk1B, Wv1B, Wk2B, Wv2B, bqc, Z, ctx);

  // ---- all four kv GEMMs in one launch, k-softmax fused ----
  kv_quad<<<640, 256, 0, stream>>>(f3p, f3b, f4p, f4b,
                                   Wk1B, Wv1B, Wk2B, Wv2B,
                                   bk1, bv1, bk2, bv2,
                                   ks3, v3b, ks4, v4b);

  // ---- fat kernel: ctx (blocks 0..319) || f2p streaming (blocks 320..4415) ----
  ctxprepB_kernel<<<4416, 256, 0, stream>>>(ks3, v3b, ks4, v4b, ctx, f2, f2pe, f2p);

  // ---- G1: E = exp(f2p @ WqB^T + bqc), Z colsums ----
  gemm_g1<<<2048, 256, 0, stream>>>(f2p, WqB, bqc, E, Z);

  // ---- fold ctx, Wr, 1/Z into per-batch Mt[b][j][c] ----
  fold_kernel<<<1024, 256, 0, stream>>>(ctx, Wr, Z, Mt);

  // ---- G2: out = E @ Mt^T + br (E still L3-hot from G1) ----
  gemm_g2<<<1024, 256, 0, stream>>>(E, Mt, br, (float*)d_out);
}

// Round 9
// 175.569 us; speedup vs baseline: 1.3263x; 1.0342x over previous
//
#include <hip/hip_runtime.h>

typedef unsigned short ushort_t;
typedef unsigned int uint32;
typedef __attribute__((ext_vector_type(8))) short short8;
typedef __attribute__((ext_vector_type(4))) float f32x4;

static __device__ __forceinline__ ushort_t f2bf(float f) {
  uint32 u = __builtin_bit_cast(uint32, f);
  u += 0x7fffu + ((u >> 16) & 1u);   // round-to-nearest-even
  return (ushort_t)(u >> 16);
}
static __device__ __forceinline__ float bf2f(ushort_t h) {
  return __builtin_bit_cast(float, (uint32)h << 16);
}

static __device__ __forceinline__ void gload_lds16(const ushort_t* g, ushort_t* l) {
  __builtin_amdgcn_global_load_lds(
      (const __attribute__((address_space(1))) uint32*)g,
      (__attribute__((address_space(3))) uint32*)l, 16, 0, 0);
}

static __device__ __forceinline__ void addcvt4(const float* __restrict__ a,
                                               const float* __restrict__ b,
                                               ushort_t* __restrict__ o, int i) {
  float4 va = reinterpret_cast<const float4*>(a)[i];
  if (b != nullptr) {
    float4 vb = reinterpret_cast<const float4*>(b)[i];
    va.x += vb.x; va.y += vb.y; va.z += vb.z; va.w += vb.w;
  }
  ushort4 u;
  u.x = f2bf(va.x); u.y = f2bf(va.y); u.z = f2bf(va.z); u.w = f2bf(va.w);
  reinterpret_cast<ushort4*>(o)[i] = u;
}

// ---------------------------------------------------------------------------
// ctx block (device func): ctx[bh,d,e] += sum_n ks[b,n,h*64+d]*v[b,n,h*64+e].
// bf16 LDS staging (17.4 KB), ushort4-vectorized. sm must hold >= 8704 ushorts.
// cb in [0,256): branch-3 (Nk=1024, 4 chunks/bh); [256,320): branch-4.
// ---------------------------------------------------------------------------
static __device__ __forceinline__ void ctx_block(
    const ushort_t* __restrict__ ks3, const ushort_t* __restrict__ v3,
    const ushort_t* __restrict__ ks4, const ushort_t* __restrict__ v4,
    float* __restrict__ ctxOut, int cb, ushort_t* sm) {
  ushort_t (*ks_s)[68] = reinterpret_cast<ushort_t(*)[68]>(sm);
  ushort_t (*v_s)[68] = reinterpret_cast<ushort_t(*)[68]>(sm + 4352);
  const int t = threadIdx.x;
  const ushort_t* ks; const ushort_t* v; float* dstBase; int Nk, bh, chunk;
  if (cb < 256) { ks = ks3; v = v3; dstBase = ctxOut;          Nk = 1024; bh = cb >> 2; chunk = cb & 3; }
  else          { ks = ks4; v = v4; dstBase = ctxOut + 262144; Nk = 256;  bh = cb - 256; chunk = 0; }
  const int bb = bh >> 3, h = bh & 7;
  const int td = t & 15, te = t >> 4;
  float acc[4][4] = {};
  size_t rowBase = (size_t)bb * Nk + chunk * 256;
  for (int n0 = 0; n0 < 256; n0 += 64) {
#pragma unroll
    for (int i = 0; i < 4; i++) {
      int idx = i * 256 + t;            // 0..1023 = 64 n x 16 quads
      int n = idx >> 4, dq = idx & 15;
      size_t g = (rowBase + n0 + n) * 512 + h * 64 + dq * 4;
      *reinterpret_cast<ushort4*>(&ks_s[n][dq * 4]) = *reinterpret_cast<const ushort4*>(ks + g);
      *reinterpret_cast<ushort4*>(&v_s[n][dq * 4]) = *reinterpret_cast<const ushort4*>(v + g);
    }
    __syncthreads();
#pragma unroll 8
    for (int n = 0; n < 64; n++) {
      ushort4 cu = *reinterpret_cast<const ushort4*>(&ks_s[n][td * 4]);
      ushort4 vu = *reinterpret_cast<const ushort4*>(&v_s[n][te * 4]);
      float ca[4] = {bf2f(cu.x), bf2f(cu.y), bf2f(cu.z), bf2f(cu.w)};
      float va[4] = {bf2f(vu.x), bf2f(vu.y), bf2f(vu.z), bf2f(vu.w)};
#pragma unroll
      for (int i = 0; i < 4; i++)
#pragma unroll
        for (int j = 0; j < 4; j++) acc[i][j] += ca[i] * va[j];
    }
    __syncthreads();
  }
  float* dst = dstBase + (size_t)bh * 4096;
#pragma unroll
  for (int i = 0; i < 4; i++)
#pragma unroll
    for (int j = 0; j < 4; j++)
      atomicAdd(&dst[(td * 4 + i) * 64 + te * 4 + j], acc[i][j]);
}

// ---------------------------------------------------------------------------
// prepA (runs FIRST): kv inputs (single pass per source), all weights fp32->bf16,
// bqc concat, Z zero, ctx zero. grid = 7169.
// ---------------------------------------------------------------------------
__global__ void prepA_kernel(const float* __restrict__ f3, const float* __restrict__ f3pe,
                             const float* __restrict__ f4, const float* __restrict__ f4pe,
                             const float* __restrict__ Wq1, const float* __restrict__ Wq2,
                             const float* __restrict__ Wk1, const float* __restrict__ Wv1,
                             const float* __restrict__ Wk2, const float* __restrict__ Wv2,
                             const float* __restrict__ bq1, const float* __restrict__ bq2,
                             ushort_t* __restrict__ f3p, ushort_t* __restrict__ f3b,
                             ushort_t* __restrict__ f4p, ushort_t* __restrict__ f4b,
                             ushort_t* __restrict__ WqB, ushort_t* __restrict__ Wk1B,
                             ushort_t* __restrict__ Wv1B, ushort_t* __restrict__ Wk2B,
                             ushort_t* __restrict__ Wv2B, float* __restrict__ bqc,
                             float* __restrict__ Z, float* __restrict__ ctx) {
  int b = blockIdx.x, t = threadIdx.x;
  if (b < 4096) {
    int i = b * 256 + t;
    float4 va = reinterpret_cast<const float4*>(f3)[i];
    float4 vp = reinterpret_cast<const float4*>(f3pe)[i];
    ushort4 ub, up;
    ub.x = f2bf(va.x); ub.y = f2bf(va.y); ub.z = f2bf(va.z); ub.w = f2bf(va.w);
    up.x = f2bf(va.x + vp.x); up.y = f2bf(va.y + vp.y);
    up.z = f2bf(va.z + vp.z); up.w = f2bf(va.w + vp.w);
    reinterpret_cast<ushort4*>(f3b)[i] = ub;
    reinterpret_cast<ushort4*>(f3p)[i] = up;
  } else if (b < 5120) {
    int i = (b - 4096) * 256 + t;
    float4 va = reinterpret_cast<const float4*>(f4)[i];
    float4 vp = reinterpret_cast<const float4*>(f4pe)[i];
    ushort4 ub, up;
    ub.x = f2bf(va.x); ub.y = f2bf(va.y); ub.z = f2bf(va.z); ub.w = f2bf(va.w);
    up.x = f2bf(va.x + vp.x); up.y = f2bf(va.y + vp.y);
    up.z = f2bf(va.z + vp.z); up.w = f2bf(va.w + vp.w);
    reinterpret_cast<ushort4*>(f4b)[i] = ub;
    reinterpret_cast<ushort4*>(f4p)[i] = up;
  } else if (b < 6656) {
    int u = b - 5120;
    int arr = u >> 8, i = (u & 255) * 256 + t;
    const float* s; ushort_t* d;
    switch (arr) {
      case 0: s = Wq1; d = WqB; break;
      case 1: s = Wq2; d = WqB + 262144; break;
      case 2: s = Wk1; d = Wk1B; break;
      case 3: s = Wv1; d = Wv1B; break;
      case 4: s = Wk2; d = Wk2B; break;
      default: s = Wv2; d = Wv2B; break;
    }
    addcvt4(s, nullptr, d, i);
  } else if (b < 7168) {
    reinterpret_cast<float4*>(ctx)[(b - 6656) * 256 + t] = make_float4(0.f, 0.f, 0.f, 0.f);
  } else {
    for (int i = t; i < 512; i += 256) { bqc[i] = bq1[i]; bqc[512 + i] = bq2[i]; }
    for (int i = t; i < 8192; i += 256) Z[i] = 0.f;
  }
}

// ---------------------------------------------------------------------------
// Shared GEMM core: 128x128 tile, 4 waves, BK=64, global_load_lds staging.
// LDS: row-major 128 x 128B, XOR-swizzle byte ^= ((row&7)<<4).
// ---------------------------------------------------------------------------
static __device__ __forceinline__ void gemm_core(
    const ushort_t* __restrict__ A, const ushort_t* __restrict__ Bt,
    int K, int mBase, int nBase, ushort_t* As, ushort_t* Bs, f32x4 acc[4][4]) {
  const int t = threadIdx.x;
  const int w = t >> 6, l = t & 63;
  const int l15 = l & 15, l4 = l >> 4;
  const int rowInSeg = l >> 3;
  const int srcOff = ((l & 7) ^ rowInSeg) << 3;
  const int wm = (w >> 1) * 64, wn = (w & 1) * 64;

  for (int k0 = 0; k0 < K; k0 += 64) {
#pragma unroll
    for (int i = 0; i < 4; i++) {
      int seg = w * 4 + i;
      int row = seg * 8 + rowInSeg;
      gload_lds16(A + (size_t)(mBase + row) * K + k0 + srcOff, As + seg * 512);
      gload_lds16(Bt + (size_t)(nBase + row) * K + k0 + srcOff, Bs + seg * 512);
    }
    __syncthreads();
#pragma unroll
    for (int kk = 0; kk < 2; kk++) {
      short8 af[4], bfr[4];
      const int kb = kk * 64 + l4 * 16;
#pragma unroll
      for (int f = 0; f < 4; f++) {
        int rowA = wm + f * 16 + l15;
        af[f] = *reinterpret_cast<const short8*>(
            reinterpret_cast<const char*>(As) + rowA * 128 + (kb ^ ((rowA & 7) << 4)));
        int rowB = wn + f * 16 + l15;
        bfr[f] = *reinterpret_cast<const short8*>(
            reinterpret_cast<const char*>(Bs) + rowB * 128 + (kb ^ ((rowB & 7) << 4)));
      }
#pragma unroll
      for (int fm = 0; fm < 4; fm++)
#pragma unroll
        for (int fn = 0; fn < 4; fn++)
          acc[fm][fn] = __builtin_amdgcn_mfma_f32_16x16x32_bf16(af[fm], bfr[fn], acc[fm][fn], 0, 0, 0);
    }
    __syncthreads();
  }
}

// ---------------------------------------------------------------------------
// G1 (+ optional fused ctx blocks): blocks [0,ctxBlocks) run ctx; the rest are
// E = exp(f2p @ WqB^T + bqc) -> bf16, colsums into Z. GEMM grid 2048 =
// 256 m x 8 n, XCD-chunked swizzle. fn-inner epilogue stores.
// ---------------------------------------------------------------------------
__global__ __launch_bounds__(256, 4)
void gemm_g1(const ushort_t* __restrict__ A, const ushort_t* __restrict__ Bt,
             const float* __restrict__ bias, ushort_t* __restrict__ E,
             float* __restrict__ Z,
             const ushort_t* __restrict__ ks3, const ushort_t* __restrict__ v3,
             const ushort_t* __restrict__ ks4, const ushort_t* __restrict__ v4,
             float* __restrict__ ctx, int ctxBlocks) {
  __shared__ ushort_t smem[16384];
  if ((int)blockIdx.x < ctxBlocks) {
    ctx_block(ks3, v3, ks4, v4, ctx, blockIdx.x, smem);
    return;
  }
  ushort_t* As = smem;
  ushort_t* Bs = smem + 8192;
  const int bid = blockIdx.x - ctxBlocks;
  const int swz = (bid & 7) * 256 + (bid >> 3);
  const int mBase = (swz >> 3) * 128, nBase = (swz & 7) * 128;
  const int t = threadIdx.x, w = t >> 6, lane = t & 63;
  const int l15 = lane & 15, l4 = lane >> 4;
  const int wm = (w >> 1) * 64, wn = (w & 1) * 64;

  f32x4 acc[4][4];
#pragma unroll
  for (int i = 0; i < 4; i++)
#pragma unroll
    for (int j = 0; j < 4; j++) acc[i][j] = (f32x4){0.f, 0.f, 0.f, 0.f};

  gemm_core(A, Bt, 512, mBase, nBase, As, Bs, acc);

  const int N = 1024;
  float bcol[4], csum[4] = {0.f, 0.f, 0.f, 0.f};
#pragma unroll
  for (int fn = 0; fn < 4; fn++) bcol[fn] = bias[nBase + wn + fn * 16 + l15];
#pragma unroll
  for (int fm = 0; fm < 4; fm++) {
#pragma unroll
    for (int r = 0; r < 4; r++) {
      int row = mBase + wm + fm * 16 + l4 * 4 + r;
      float ex[4];
#pragma unroll
      for (int fn = 0; fn < 4; fn++) {
        ex[fn] = __expf(acc[fm][fn][r] + bcol[fn]);
        csum[fn] += ex[fn];
      }
#pragma unroll
      for (int fn = 0; fn < 4; fn++)
        E[(size_t)row * N + nBase + wn + fn * 16 + l15] = f2bf(ex[fn]);
    }
  }
#pragma unroll
  for (int fn = 0; fn < 4; fn++) {
    float s = csum[fn];
    s += __shfl_xor(s, 16);
    s += __shfl_xor(s, 32);
    if (l4 == 0) atomicAdd(&Z[(mBase >> 12) * 1024 + nBase + wn + fn * 16 + l15], s);
  }
}

// ---------------------------------------------------------------------------
// KV quad (+ optional fused f2p stream): blocks [0,640) = four kv GEMMs
// (N=512, K=512) with fused k-softmax; blocks >= 640 stream
// f2p = bf16(f2+f2pe), 2048 float4/block (8 iters, 8 loads in flight).
// ---------------------------------------------------------------------------
__global__ __launch_bounds__(256, 4)
void kv_quad(const ushort_t* __restrict__ f3p, const ushort_t* __restrict__ f3b,
             const ushort_t* __restrict__ f4p, const ushort_t* __restrict__ f4b,
             const ushort_t* __restrict__ Wk1B, const ushort_t* __restrict__ Wv1B,
             const ushort_t* __restrict__ Wk2B, const ushort_t* __restrict__ Wv2B,
             const float* __restrict__ bk1, const float* __restrict__ bv1,
             const float* __restrict__ bk2, const float* __restrict__ bv2,
             ushort_t* __restrict__ ks3, ushort_t* __restrict__ v3,
             ushort_t* __restrict__ ks4, ushort_t* __restrict__ v4,
             const float* __restrict__ f2, const float* __restrict__ f2pe,
             ushort_t* __restrict__ f2p) {
  __shared__ ushort_t As[8192], Bs[8192];
  const int bid = blockIdx.x;
  if (bid >= 640) {
    const int base = (bid - 640) * 2048;
    const float4* A4 = reinterpret_cast<const float4*>(f2);
    const float4* P4 = reinterpret_cast<const float4*>(f2pe);
    const int t = threadIdx.x;
#pragma unroll
    for (int half = 0; half < 2; half++) {
      float4 a[4], p[4];
#pragma unroll
      for (int j = 0; j < 4; j++) {
        int i = base + (half * 4 + j) * 256 + t;
        a[j] = A4[i];
        p[j] = P4[i];
      }
#pragma unroll
      for (int j = 0; j < 4; j++) {
        int i = base + (half * 4 + j) * 256 + t;
        ushort4 u;
        u.x = f2bf(a[j].x + p[j].x); u.y = f2bf(a[j].y + p[j].y);
        u.z = f2bf(a[j].z + p[j].z); u.w = f2bf(a[j].w + p[j].w);
        reinterpret_cast<ushort4*>(f2p)[i] = u;
      }
    }
    return;
  }
  const int id = (bid & 7) * 80 + (bid >> 3);
  const ushort_t* A; const ushort_t* Bt; const float* bias; ushort_t* out;
  bool doSM; int loc;
  if (id < 256)      { A = f3p; Bt = Wk1B; bias = bk1; out = ks3; doSM = true;  loc = id; }
  else if (id < 512) { A = f3b; Bt = Wv1B; bias = bv1; out = v3;  doSM = false; loc = id - 256; }
  else if (id < 576) { A = f4p; Bt = Wk2B; bias = bk2; out = ks4; doSM = true;  loc = id - 512; }
  else               { A = f4b; Bt = Wv2B; bias = bv2; out = v4;  doSM = false; loc = id - 576; }
  const int nBase = (loc & 3) * 128, mBase = (loc >> 2) * 128;
  const int t = threadIdx.x, w = t >> 6, lane = t & 63;
  const int l15 = lane & 15, l4 = lane >> 4;
  const int wm = (w >> 1) * 64, wn = (w & 1) * 64;

  f32x4 acc[4][4];
#pragma unroll
  for (int i = 0; i < 4; i++)
#pragma unroll
    for (int j = 0; j < 4; j++) acc[i][j] = (f32x4){0.f, 0.f, 0.f, 0.f};

  gemm_core(A, Bt, 512, mBase, nBase, As, Bs, acc);

  const int N = 512;
  float bcol[4];
#pragma unroll
  for (int fn = 0; fn < 4; fn++) bcol[fn] = bias[nBase + wn + fn * 16 + l15];

  if (doSM) {
#pragma unroll
    for (int fm = 0; fm < 4; fm++) {
#pragma unroll
      for (int r = 0; r < 4; r++) {
        float x[4], m = -1e30f;
#pragma unroll
        for (int fn = 0; fn < 4; fn++) { x[fn] = acc[fm][fn][r] + bcol[fn]; m = fmaxf(m, x[fn]); }
        m = fmaxf(m, __shfl_xor(m, 1));
        m = fmaxf(m, __shfl_xor(m, 2));
        m = fmaxf(m, __shfl_xor(m, 4));
        m = fmaxf(m, __shfl_xor(m, 8));
        float s = 0.f;
#pragma unroll
        for (int fn = 0; fn < 4; fn++) { x[fn] = __expf(x[fn] - m); s += x[fn]; }
        s += __shfl_xor(s, 1);
        s += __shfl_xor(s, 2);
        s += __shfl_xor(s, 4);
        s += __shfl_xor(s, 8);
        float inv = 1.f / s;
        int row = mBase + wm + fm * 16 + l4 * 4 + r;
#pragma unroll
        for (int fn = 0; fn < 4; fn++)
          out[(size_t)row * N + nBase + wn + fn * 16 + l15] = f2bf(x[fn] * inv);
      }
    }
  } else {
#pragma unroll
    for (int fm = 0; fm < 4; fm++) {
#pragma unroll
      for (int r = 0; r < 4; r++) {
        int row = mBase + wm + fm * 16 + l4 * 4 + r;
#pragma unroll
        for (int fn = 0; fn < 4; fn++)
          out[(size_t)row * N + nBase + wn + fn * 16 + l15] =
              f2bf(acc[fm][fn][r] + bcol[fn]);
      }
    }
  }
}

// ---------------------------------------------------------------------------
// ctxprepB (fallback path, small ws): blocks 0..319 ctx (bf16 LDS, 17.4 KB);
// blocks 320..4415 stream f2p = bf16(f2+f2pe).
// ---------------------------------------------------------------------------
__global__ __launch_bounds__(256)
void ctxprepB_kernel(const ushort_t* __restrict__ ks3, const ushort_t* __restrict__ v3,
                     const ushort_t* __restrict__ ks4, const ushort_t* __restrict__ v4,
                     float* __restrict__ ctxOut,
                     const float* __restrict__ f2, const float* __restrict__ f2pe,
                     ushort_t* __restrict__ f2p) {
  __shared__ ushort_t sm[8704];
  const int b = blockIdx.x, t = threadIdx.x;
  if (b >= 320) {
    const int base = (b - 320) * 1024;
    const float4* A4 = reinterpret_cast<const float4*>(f2);
    const float4* P4 = reinterpret_cast<const float4*>(f2pe);
#pragma unroll
    for (int j = 0; j < 4; j++) {
      int i = base + j * 256 + t;
      float4 a = A4[i], p = P4[i];
      ushort4 u;
      u.x = f2bf(a.x + p.x); u.y = f2bf(a.y + p.y);
      u.z = f2bf(a.z + p.z); u.w = f2bf(a.w + p.w);
      reinterpret_cast<ushort4*>(f2p)[i] = u;
    }
    return;
  }
  ctx_block(ks3, v3, ks4, v4, ctxOut, b, sm);
}

// ---------------------------------------------------------------------------
// G2: out_fp32 = E @ Mt(batch)^T + br.  grid 1024 = 256 m x 4 n, XCD swizzle.
// ---------------------------------------------------------------------------
__global__ __launch_bounds__(256, 4)
void gemm_g2(const ushort_t* __restrict__ E, const ushort_t* __restrict__ Mt,
             const float* __restrict__ bias, float* __restrict__ C) {
  __shared__ ushort_t As[8192], Bs[8192];
  const int bid = blockIdx.x;
  const int swz = (bid & 7) * 128 + (bid >> 3);
  const int tx = swz & 3, ty = swz >> 2;
  const int mBase = ty * 128, nBase = tx * 128;
  const ushort_t* Btb = Mt + (size_t)(ty >> 5) * 524288;
  const int t = threadIdx.x, w = t >> 6, lane = t & 63;
  const int l15 = lane & 15, l4 = lane >> 4;
  const int wm = (w >> 1) * 64, wn = (w & 1) * 64;

  f32x4 acc[4][4];
#pragma unroll
  for (int i = 0; i < 4; i++)
#pragma unroll
    for (int j = 0; j < 4; j++) acc[i][j] = (f32x4){0.f, 0.f, 0.f, 0.f};

  gemm_core(E, Btb, 1024, mBase, nBase, As, Bs, acc);

  const int N = 512;
  float bcol[4];
#pragma unroll
  for (int fn = 0; fn < 4; fn++) bcol[fn] = bias[nBase + wn + fn * 16 + l15];
#pragma unroll
  for (int fm = 0; fm < 4; fm++) {
#pragma unroll
    for (int r = 0; r < 4; r++) {
      int row = mBase + wm + fm * 16 + l4 * 4 + r;
#pragma unroll
      for (int fn = 0; fn < 4; fn++)
        C[(size_t)row * N + nBase + wn + fn * 16 + l15] = acc[fm][fn][r] + bcol[fn];
    }
  }
}

// ---------------------------------------------------------------------------
// Fold: Mt[b][j][c] = (sum_e ctx[branch,b,h,d,e]*Wr[j, branch*512+h*64+e]) / Z[b,c]
// ---------------------------------------------------------------------------
__global__ __launch_bounds__(256)
void fold_kernel(const float* __restrict__ ctx, const float* __restrict__ Wr,
                 const float* __restrict__ Z, ushort_t* __restrict__ Mt) {
  __shared__ float ctxT[64][68];   // [e][d]
  __shared__ float wrT[64][68];    // [e][jl]
  __shared__ float zinv[64];
  int blk = blockIdx.x;
  int jc = blk & 7;
  int h = (blk >> 3) & 7;
  int branch = (blk >> 6) & 1;
  int b = blk >> 7;
  int t = threadIdx.x;
  int cbase = branch * 512 + h * 64;
  const float* csrc = ctx + (size_t)(branch * 64 + b * 8 + h) * 4096;
#pragma unroll
  for (int i = 0; i < 16; i++) {
    int idx = i * 256 + t;
    int d = idx >> 6, e = idx & 63;
    ctxT[e][d] = csrc[d * 64 + e];
  }
#pragma unroll
  for (int i = 0; i < 16; i++) {
    int idx = i * 256 + t;
    int jl = idx >> 6, e = idx & 63;
    wrT[e][jl] = Wr[(size_t)(jc * 64 + jl) * 1024 + cbase + e];
  }
  if (t < 64) zinv[t] = 1.0f / Z[b * 1024 + cbase + t];
  __syncthreads();
  int td = t & 15, tj = t >> 4;
  float acc[4][4] = {};   // [d_i][jj]
#pragma unroll 8
  for (int e = 0; e < 64; e++) {
    float4 cv = *reinterpret_cast<const float4*>(&ctxT[e][td * 4]);
    float4 wv = *reinterpret_cast<const float4*>(&wrT[e][tj * 4]);
    float ca[4] = {cv.x, cv.y, cv.z, cv.w};
    float wa[4] = {wv.x, wv.y, wv.z, wv.w};
#pragma unroll
    for (int i = 0; i < 4; i++)
#pragma unroll
      for (int jj = 0; jj < 4; jj++) acc[i][jj] += ca[i] * wa[jj];
  }
  float zi[4] = {zinv[td * 4], zinv[td * 4 + 1], zinv[td * 4 + 2], zinv[td * 4 + 3]};
#pragma unroll
  for (int jj = 0; jj < 4; jj++) {
    ushort4 u;
    u.x = f2bf(acc[0][jj] * zi[0]);
    u.y = f2bf(acc[1][jj] * zi[1]);
    u.z = f2bf(acc[2][jj] * zi[2]);
    u.w = f2bf(acc[3][jj] * zi[3]);
    *reinterpret_cast<ushort4*>(
        &Mt[(size_t)(b * 512 + jc * 64 + tj * 4 + jj) * 1024 + cbase + td * 4]) = u;
  }
}

// ---------------------------------------------------------------------------
extern "C" void kernel_launch(void* const* d_in, const int* in_sizes, int n_in,
                              void* d_out, int out_size, void* d_ws, size_t ws_size,
                              hipStream_t stream) {
  const float* f2 = (const float*)d_in[0];
  const float* f3 = (const float*)d_in[1];
  const float* f4 = (const float*)d_in[2];
  const float* f2pe = (const float*)d_in[3];
  const float* f3pe = (const float*)d_in[4];
  const float* f4pe = (const float*)d_in[5];
  const float* Wq1 = (const float*)d_in[6];
  const float* bq1 = (const float*)d_in[7];
  const float* Wk1 = (const float*)d_in[8];
  const float* bk1 = (const float*)d_in[9];
  const float* Wv1 = (const float*)d_in[10];
  const float* bv1 = (const float*)d_in[11];
  const float* Wq2 = (const float*)d_in[12];
  const float* bq2 = (const float*)d_in[13];
  const float* Wk2 = (const float*)d_in[14];
  const float* bk2 = (const float*)d_in[15];
  const float* Wv2 = (const float*)d_in[16];
  const float* bv2 = (const float*)d_in[17];
  const float* Wr = (const float*)d_in[18];
  const float* br = (const float*)d_in[19];

  char* ws = (char*)d_ws;
  // Region 0: E bf16 [32768,1024]
  ushort_t* E = (ushort_t*)(ws + 0);                       // 67,108,864 B
  // Region 1 (33.5 MB): kv inputs; small-ws path reuses it for f2p after kvq
  char* R1 = ws + 67108864;
  ushort_t* f3p = (ushort_t*)R1;                           // 8,388,608
  ushort_t* f3b = (ushort_t*)(R1 + 8388608);               // 8,388,608
  ushort_t* f4p = (ushort_t*)(R1 + 16777216);              // 2,097,152
  ushort_t* f4b = (ushort_t*)(R1 + 18874368);              // 2,097,152
  // Region 2: kv GEMM outputs (softmaxed k + v, bf16)
  char* R2 = ws + 100663296;
  ushort_t* ks3 = (ushort_t*)R2;
  ushort_t* v3b = (ushort_t*)(R2 + 8388608);
  ushort_t* ks4 = (ushort_t*)(R2 + 16777216);
  ushort_t* v4b = (ushort_t*)(R2 + 18874368);
  // Region 3: weights bf16, Mt, Z, bqc, ctx
  char* R3 = ws + 121634816;
  ushort_t* WqB = (ushort_t*)R3;                           // 1,048,576
  ushort_t* Wk1B = (ushort_t*)(R3 + 1048576);
  ushort_t* Wv1B = (ushort_t*)(R3 + 1572864);
  ushort_t* Wk2B = (ushort_t*)(R3 + 2097152);
  ushort_t* Wv2B = (ushort_t*)(R3 + 2621440);
  ushort_t* Mt = (ushort_t*)(R3 + 3145728);                // 8,388,608
  float* Z = (float*)(R3 + 11534336);                      // 32,768
  float* bqc = (float*)(R3 + 11567104);                    // 4,096
  float* ctx = (float*)(R3 + 11571200);                    // 2,097,152
  // Region 4 (big-ws only): dedicated f2p, disjoint from all live buffers
  const bool bigWS = ws_size >= (size_t)176160768;         // needs 168 MiB
  ushort_t* f2p = bigWS ? (ushort_t*)(ws + 142606336) : (ushort_t*)R1;

  // ---- prepA: kv inputs, weights->bf16, bqc, Z=0, ctx=0 ----
  prepA_kernel<<<7169, 256, 0, stream>>>(f3, f3pe, f4, f4pe,
                                         Wq1, Wq2, Wk1, Wv1, Wk2, Wv2, bq1, bq2,
                                         f3p, f3b, f4p, f4b,
                                         WqB, Wk1B, Wv1B, Wk2B, Wv2B, bqc, Z, ctx);

  if (bigWS) {
    // kv GEMMs (640 blocks) || f2p stream (2048 blocks) in one launch
    kv_quad<<<2688, 256, 0, stream>>>(f3p, f3b, f4p, f4b,
                                      Wk1B, Wv1B, Wk2B, Wv2B,
                                      bk1, bv1, bk2, bv2,
                                      ks3, v3b, ks4, v4b, f2, f2pe, f2p);
    // ctx (320 leading blocks) || G1 GEMM (2048 blocks)
    gemm_g1<<<2368, 256, 0, stream>>>(f2p, WqB, bqc, E, Z,
                                      ks3, v3b, ks4, v4b, ctx, 320);
  } else {
    kv_quad<<<640, 256, 0, stream>>>(f3p, f3b, f4p, f4b,
                                     Wk1B, Wv1B, Wk2B, Wv2B,
                                     bk1, bv1, bk2, bv2,
                                     ks3, v3b, ks4, v4b, f2, f2pe, f2p);
    // ctx (320) || f2p stream (4096) — f2p reuses dead kv-input space
    ctxprepB_kernel<<<4416, 256, 0, stream>>>(ks3, v3b, ks4, v4b, ctx, f2, f2pe, f2p);
    gemm_g1<<<2048, 256, 0, stream>>>(f2p, WqB, bqc, E, Z,
                                      ks3, v3b, ks4, v4b, ctx, 0);
  }

  // ---- fold ctx, Wr, 1/Z into per-batch Mt[b][j][c] ----
  fold_kernel<<<1024, 256, 0, stream>>>(ctx, Wr, Z, Mt);

  // ---- G2: out = E @ Mt^T + br (E L3-hot from G1) ----
  gemm_g2<<<1024, 256, 0, stream>>>(E, Mt, br, (float*)d_out);
}